// Round 5
// baseline (702.264 us; speedup 1.0000x reference)
//
#include <hip/hip_runtime.h>

#define NNODE 10000
#define NEDGE 160000
#define DD 256

using f32x4  = __attribute__((ext_vector_type(4))) float;
using bf16x8 = __attribute__((ext_vector_type(8))) short;
using u32x4  = __attribute__((ext_vector_type(4))) unsigned;

#define WAITV(N) asm volatile("s_waitcnt vmcnt(" #N ")" ::: "memory")

__device__ inline short f2bf(float f) {
  unsigned u = __float_as_uint(f);
  unsigned r = (u + 0x7fffu + ((u >> 16) & 1u)) >> 16;
  return (short)(unsigned short)r;
}

__device__ inline unsigned pkbf(float a, float b) {
  unsigned r;
  asm("v_cvt_pk_bf16_f32 %0, %1, %2" : "=v"(r) : "v"(a), "v"(b));
  return r;
}

__global__ void cast_x_kernel(const float* __restrict__ x, short* __restrict__ xb, int total) {
  int i = blockIdx.x * 256 + threadIdx.x;
  if (i < total) xb[i] = f2bf(x[i]);
}

// pack w[K][N] (f32) -> p[(k>>3)][n][k&7] (bf16)
__global__ void pack_w_kernel(const float* __restrict__ w, short* __restrict__ p, int K, int N) {
  int idx = blockIdx.x * 256 + threadIdx.x;
  if (idx >= K * N) return;
  int k = idx / N, n = idx - k * N;
  p[(size_t)(k >> 3) * N * 8 + (size_t)n * 8 + (k & 7)] = f2bf(w[idx]);
}

// ---------------- CSR build ----------------
__global__ void hist_kernel(const int* __restrict__ ei, int* __restrict__ deg) {
  int e = blockIdx.x * 256 + threadIdx.x;
  if (e < NEDGE) {
    int j = ei[NEDGE + e]; j = min(max(j, 0), NNODE - 1);
    atomicAdd(&deg[j], 1);
  }
}

__global__ void scan_kernel(const int* __restrict__ deg, int* __restrict__ row_start) {
  __shared__ int part[256];
  int t = threadIdx.x;
  const int CH = 40;
  int base = t * CH;
  int s = 0;
  for (int i = 0; i < CH; i++) {
    int idx = base + i;
    s += (idx < NNODE) ? deg[idx] : 0;
  }
  part[t] = s;
  __syncthreads();
  for (int off = 1; off < 256; off <<= 1) {
    int v = (t >= off) ? part[t - off] : 0;
    __syncthreads();
    part[t] += v;
    __syncthreads();
  }
  int run = (t == 0) ? 0 : part[t - 1];
  for (int i = 0; i < CH; i++) {
    int idx = base + i;
    if (idx < NNODE) { row_start[idx] = run; run += deg[idx]; }
  }
  if (t == 255) row_start[NNODE] = part[255];
}

__global__ void scatter_kernel(const int* __restrict__ ei, const int* __restrict__ row_start,
                               int* __restrict__ cursor, int* __restrict__ csr) {
  int e = blockIdx.x * 256 + threadIdx.x;
  if (e < NEDGE) {
    int j = ei[NEDGE + e]; j = min(max(j, 0), NNODE - 1);
    int p = atomicAdd(&cursor[j], 1);
    csr[row_start[j] + p] = e;
  }
}

__global__ __launch_bounds__(256) void agg_kernel(const float* __restrict__ out_e,
                                                  const int* __restrict__ row_start,
                                                  const int* __restrict__ csr,
                                                  short* __restrict__ aggb) {
  int node = blockIdx.x * 4 + (threadIdx.x >> 6);
  int lane = threadIdx.x & 63;
  if (node >= NNODE) return;
  int rs = row_start[node], re = row_start[node + 1];
  float4 acc = {0.f, 0.f, 0.f, 0.f};
  for (int k = rs; k < re; k++) {
    int eid = csr[k];
    float4 v = *(const float4*)(out_e + (size_t)eid * DD + lane * 4);
    acc.x += v.x; acc.y += v.y; acc.z += v.z; acc.w += v.w;
  }
  short4 o;
  o.x = f2bf(acc.x); o.y = f2bf(acc.y); o.z = f2bf(acc.z); o.w = f2bf(acc.w);
  *(short4*)(aggb + (size_t)node * DD + lane * 4) = o;
}

// MODE 0: edge (K1=768, A = x[i] | x[j] | ea, residual=ea)
// MODE 1: node (K1=512, A = x | agg(bf16), residual=x)
// Single K-sweep GEMM1; ring-4 LDS stage buffers; counted vmcnt + raw s_barrier
// (one barrier/stage, loads stay in flight 2 stages deep). ea f32 loaded ONCE in
// prologue, held as bf16 in regs, staged via ds_write (stages 8-11 issue no vmem).
template<int MODE>
__global__ __launch_bounds__(256, 2)
void fused_mlp(const float* __restrict__ x,
               const short* __restrict__ xb,
               const int*   __restrict__ ei,
               const float* __restrict__ ea,
               const short* __restrict__ aggb,
               const short* __restrict__ w1p,
               const float* __restrict__ b1,
               const short* __restrict__ w2p,
               const float* __restrict__ b2,
               const float* __restrict__ gam,
               const float* __restrict__ bet,
               float*       __restrict__ out)
{
  constexpr int K1  = (MODE == 0) ? 768 : 512;
  constexpr int NST = K1 / 64;          // 12 | 8 stages
  constexpr int HP  = 520;              // hidden pitch (bf16)

  // LDS union: abuf ring-4 (32 KB) and hid (66.6 KB) are temporally disjoint.
  __shared__ __align__(16) char smem[64 * HP * 2 + 512 + 2048];
  short* abuf = (short*)smem;                    // [4][4096] shorts (ring)
  short* hid  = (short*)smem;                    // [64][520]
  int*   idxi = (int*)(smem + 64 * HP * 2);      // [64]
  int*   idxj = idxi + 64;                       // [64]
  float* pS   = (float*)(smem + 64 * HP * 2 + 512);   // [4][64]
  float* pQ   = pS + 256;                        // [4][64]

  const int tid  = threadIdx.x;
  const int lane = tid & 63;
  const int wid  = tid >> 6;
  const int m0   = blockIdx.x * 64;
  const int lhi  = lane >> 4;
  const int llo  = lane & 15;
  const int swz  = llo & 7;

  if (MODE == 0) {
    if (tid < 64) {
      int a = ei[m0 + tid];
      int b = ei[NEDGE + m0 + tid];
      idxi[tid] = min(max(a, 0), NNODE - 1);
      idxj[tid] = min(max(b, 0), NNODE - 1);
    }
    __syncthreads();
  }

  // Staging geometry (R4-verified): chunk c = half*256 + tid -> row = c>>3,
  // seg0 = c&7; lane fetches global k-window seg0 ^ (row&7) (both-sides XOR).
  const int row0 = tid >> 3;
  const int row1 = 32 + (tid >> 3);
  const int es0  = (((tid & 7) ^ (row0 & 7)) * 8);
  const int es1  = (((tid & 7) ^ (row1 & 7)) * 8);
  int offI0, offI1, offJ0, offJ1, offE0, offE1;
  if (MODE == 0) {
    offI0 = idxi[row0] * 512 + es0 * 2;   offI1 = idxi[row1] * 512 + es1 * 2;
    offJ0 = idxj[row0] * 512 + es0 * 2;   offJ1 = idxj[row1] * 512 + es1 * 2;
    offE0 = (m0 + row0) * 1024 + es0 * 4; offE1 = (m0 + row1) * 1024 + es1 * 4;
  } else {
    int r0 = min(m0 + row0, NNODE - 1), r1 = min(m0 + row1, NNODE - 1);
    offI0 = r0 * 512 + es0 * 2;  offI1 = r1 * 512 + es1 * 2;
    offJ0 = r0 * 512 + es0 * 2;  offJ1 = r1 * 512 + es1 * 2;
    offE0 = 0; offE1 = 0;
  }

  // ---- prologue: read ea (f32) ONCE, convert, hold as bf16 in 32 regs ----
  u32x4 eq0[4], eq1[4];
  if (MODE == 0) {
    #pragma unroll
    for (int t = 0; t < 4; t++) {
      const float4* f0 = (const float4*)((const char*)ea + offE0 + t * 256);
      const float4* f1 = (const float4*)((const char*)ea + offE1 + t * 256);
      float4 a0 = f0[0], a1 = f0[1], c0 = f1[0], c1 = f1[1];
      eq0[t] = u32x4{ pkbf(a0.x, a0.y), pkbf(a0.z, a0.w), pkbf(a1.x, a1.y), pkbf(a1.z, a1.w) };
      eq1[t] = u32x4{ pkbf(c0.x, c0.y), pkbf(c0.z, c0.w), pkbf(c1.x, c1.y), pkbf(c1.z, c1.w) };
    }
  }

  auto STAGE = [&](int buf, int k0) {
    short* db = abuf + buf * 4096;
    if (k0 < 512 || MODE == 1) {
      const char* base;
      int o0, o1;
      if (k0 < 256) {
        base = (const char*)xb;
        o0 = offI0 + k0 * 2; o1 = offI1 + k0 * 2;
      } else {
        base = (MODE == 0) ? (const char*)xb : (const char*)aggb;
        o0 = offJ0 + (k0 - 256) * 2; o1 = offJ1 + (k0 - 256) * 2;
      }
      __builtin_amdgcn_global_load_lds((const int*)(base + o0),
                                       (int*)(db + wid * 512), 16, 0, 0);
      __builtin_amdgcn_global_load_lds((const int*)(base + o1),
                                       (int*)(db + 2048 + wid * 512), 16, 0, 0);
    } else {
      const int t = (k0 >> 6) - 8;          // 0..3, compile-time
      *(u32x4*)(db + tid * 8)        = eq0[t];
      *(u32x4*)(db + 2048 + tid * 8) = eq1[t];
    }
  };

  f32x4 acc1[4][8] = {};
  const bf16x8* bp1 = (const bf16x8*)w1p;
  const int bcol1 = wid * 128 + llo;

  // ---------------- GEMM1: single K-sweep, counted-vmcnt pipeline ----------------
  STAGE(0, 0);
  STAGE(1, 64);
  #pragma unroll
  for (int s = 0; s < NST; s++) {
    if (s + 2 < NST) STAGE((s + 2) & 3, (s + 2) * 64);
    // stage s's loads (if any) have >=4 / >=2 / 0 younger vmem ops -> safe waits
    if (s < 8) {
      if (s + 2 < 8)      WAITV(4);
      else if (s + 1 < 8) WAITV(2);
      else                WAITV(0);
    }
    __builtin_amdgcn_s_barrier();
    asm volatile("" ::: "memory");

    const short* ab = abuf + (s & 3) * 4096;
    #pragma unroll
    for (int kk = 0; kk < 64; kk += 32) {
      bf16x8 a[4];
      const int seg = ((kk >> 3) + lhi) ^ swz;
      #pragma unroll
      for (int mf = 0; mf < 4; mf++)
        a[mf] = *(const bf16x8*)(ab + (mf * 16 + llo) * 64 + seg * 8);
      const bf16x8* bb = bp1 + (size_t)(s * 8 + (kk >> 3) + lhi) * 512 + bcol1;
      #pragma unroll
      for (int nf = 0; nf < 8; nf++) {
        bf16x8 b = bb[nf * 16];
        #pragma unroll
        for (int mf = 0; mf < 4; mf++)
          acc1[mf][nf] = __builtin_amdgcn_mfma_f32_16x16x32_bf16(a[mf], b, acc1[mf][nf], 0, 0, 0);
      }
    }
  }
  __syncthreads();   // all waves done reading abuf before hid overwrites it

  // ---------------- bias + relu -> hidden bf16 in LDS ----------------
  #pragma unroll
  for (int nf = 0; nf < 8; nf++) {
    int col = wid * 128 + nf * 16 + llo;
    float bb = b1[col];
    #pragma unroll
    for (int mf = 0; mf < 4; mf++) {
      #pragma unroll
      for (int r = 0; r < 4; r++) {
        float v = acc1[mf][nf][r] + bb;
        v = v > 0.f ? v : 0.f;
        hid[(mf * 16 + lhi * 4 + r) * HP + col] = f2bf(v);
      }
    }
  }
  __syncthreads();

  // ---------------- GEMM2: [64 x 512] @ [512 x 256] ----------------
  f32x4 acc2[4][4] = {};
  const bf16x8* bp2 = (const bf16x8*)w2p;
  const int bcol2 = wid * 64 + llo;
  #pragma unroll
  for (int kk = 0; kk < 512; kk += 32) {
    bf16x8 a[4];
    #pragma unroll
    for (int mf = 0; mf < 4; mf++)
      a[mf] = *(const bf16x8*)(hid + (mf * 16 + llo) * HP + kk + lhi * 8);
    const bf16x8* bb = bp2 + (size_t)((kk >> 3) + lhi) * 256 + bcol2;
    #pragma unroll
    for (int nf = 0; nf < 4; nf++) {
      bf16x8 b = bb[nf * 16];
      #pragma unroll
      for (int mf = 0; mf < 4; mf++)
        acc2[mf][nf] = __builtin_amdgcn_mfma_f32_16x16x32_bf16(a[mf], b, acc2[mf][nf], 0, 0, 0);
    }
  }

  // ---------------- LayerNorm in registers ----------------
  float bb2[4], gg[4], be[4];
  #pragma unroll
  for (int nf = 0; nf < 4; nf++) {
    int col = bcol2 + nf * 16;
    bb2[nf] = b2[col]; gg[nf] = gam[col]; be[nf] = bet[col];
  }
  #pragma unroll
  for (int mf = 0; mf < 4; mf++)
    #pragma unroll
    for (int nf = 0; nf < 4; nf++)
      #pragma unroll
      for (int r = 0; r < 4; r++)
        acc2[mf][nf][r] += bb2[nf];

  float S[4][4], Q[4][4];
  #pragma unroll
  for (int mf = 0; mf < 4; mf++) {
    #pragma unroll
    for (int r = 0; r < 4; r++) {
      float s = 0.f, q = 0.f;
      #pragma unroll
      for (int nf = 0; nf < 4; nf++) {
        float v = acc2[mf][nf][r];
        s += v; q += v * v;
      }
      S[mf][r] = s; Q[mf][r] = q;
    }
  }
  #pragma unroll
  for (int m = 1; m <= 8; m <<= 1) {
    #pragma unroll
    for (int mf = 0; mf < 4; mf++)
      #pragma unroll
      for (int r = 0; r < 4; r++) {
        S[mf][r] += __shfl_xor(S[mf][r], m);
        Q[mf][r] += __shfl_xor(Q[mf][r], m);
      }
  }
  if (llo == 0) {
    #pragma unroll
    for (int mf = 0; mf < 4; mf++)
      #pragma unroll
      for (int r = 0; r < 4; r++) {
        int row = mf * 16 + lhi * 4 + r;
        pS[wid * 64 + row] = S[mf][r];
        pQ[wid * 64 + row] = Q[mf][r];
      }
  }
  __syncthreads();

  float mu[4][4], rsv[4][4];
  #pragma unroll
  for (int mf = 0; mf < 4; mf++) {
    #pragma unroll
    for (int r = 0; r < 4; r++) {
      int row = mf * 16 + lhi * 4 + r;
      float s = pS[row] + pS[64 + row] + pS[128 + row] + pS[192 + row];
      float q = pQ[row] + pQ[64 + row] + pQ[128 + row] + pQ[192 + row];
      float m_ = s * (1.f / 256.f);
      mu[mf][r]  = m_;
      rsv[mf][r] = rsqrtf(q * (1.f / 256.f) - m_ * m_ + 1e-5f);
    }
  }

  // ---------------- normalize + residual + store ----------------
  const float* resb = (MODE == 0) ? ea : x;
  #pragma unroll
  for (int mf = 0; mf < 4; mf++) {
    #pragma unroll
    for (int r = 0; r < 4; r++) {
      int grow = m0 + mf * 16 + lhi * 4 + r;
      if (MODE == 1 && grow >= NNODE) continue;
      const float* rp = resb + (size_t)grow * DD + bcol2;
      float*       op = out  + (size_t)grow * DD + bcol2;
      #pragma unroll
      for (int nf = 0; nf < 4; nf++) {
        float v = (acc2[mf][nf][r] - mu[mf][r]) * rsv[mf][r] * gg[nf] + be[nf] + rp[nf * 16];
        op[nf * 16] = v;
      }
    }
  }
}

extern "C" void kernel_launch(void* const* d_in, const int* in_sizes, int n_in,
                              void* d_out, int out_size, void* d_ws, size_t ws_size,
                              hipStream_t stream) {
  const float* x      = (const float*)d_in[0];
  const int*   ei     = (const int*)  d_in[1];
  const float* ea     = (const float*)d_in[2];
  const float* e_w1   = (const float*)d_in[3];
  const float* e_b1   = (const float*)d_in[4];
  const float* e_w2   = (const float*)d_in[5];
  const float* e_b2   = (const float*)d_in[6];
  const float* e_g    = (const float*)d_in[7];
  const float* e_beta = (const float*)d_in[8];
  const float* n_w1   = (const float*)d_in[9];
  const float* n_b1   = (const float*)d_in[10];
  const float* n_w2   = (const float*)d_in[11];
  const float* n_b2   = (const float*)d_in[12];
  const float* n_g    = (const float*)d_in[13];
  const float* n_beta = (const float*)d_in[14];

  float* out_x = (float*)d_out;
  float* out_e = (float*)d_out + (size_t)NNODE * DD;

  char* w = (char*)d_ws;
  short* xb   = (short*)(w);                    // 5,120,000 B
  short* ew1p = (short*)(w + 5120000);          //   786,432 B
  short* nw1p = (short*)(w + 5906432);          //   524,288 B
  short* ew2p = (short*)(w + 6430720);          //   262,144 B
  short* nw2p = (short*)(w + 6692864);          //   262,144 B
  short* aggb = (short*)(w + 6955008);          // 5,120,000 B
  int*   deg  = (int*)  (w + 12075008);         //    40,960 B
  int*   cur  = (int*)  (w + 12115968);         //    40,960 B
  int*   rs   = (int*)  (w + 12156928);         //    40,976 B
  int*   csr  = (int*)  (w + 12197904);         //   640,000 B

  hipMemsetAsync(deg, 0, 81920, stream);  // deg + cursor

  cast_x_kernel<<<(NNODE * DD + 255) / 256, 256, 0, stream>>>(x, xb, NNODE * DD);
  pack_w_kernel<<<(768 * 512 + 255) / 256, 256, 0, stream>>>(e_w1, ew1p, 768, 512);
  pack_w_kernel<<<(512 * 512 + 255) / 256, 256, 0, stream>>>(n_w1, nw1p, 512, 512);
  pack_w_kernel<<<(512 * 256 + 255) / 256, 256, 0, stream>>>(e_w2, ew2p, 512, 256);
  pack_w_kernel<<<(512 * 256 + 255) / 256, 256, 0, stream>>>(n_w2, nw2p, 512, 256);

  hist_kernel<<<(NEDGE + 255) / 256, 256, 0, stream>>>(ei, deg);
  scan_kernel<<<1, 256, 0, stream>>>(deg, rs);
  scatter_kernel<<<(NEDGE + 255) / 256, 256, 0, stream>>>(ei, rs, cur, csr);

  fused_mlp<0><<<NEDGE / 64, 256, 0, stream>>>(x, xb, ei, ea, aggb,
                                               ew1p, e_b1, ew2p, e_b2, e_g, e_beta, out_e);
  agg_kernel<<<(NNODE + 3) / 4, 256, 0, stream>>>(out_e, rs, csr, aggb);
  fused_mlp<1><<<(NNODE + 63) / 64, 256, 0, stream>>>(x, xb, ei, ea, aggb,
                                                      nw1p, n_b1, nw2p, n_b2, n_g, n_beta, out_x);
}

// Round 6
// 532.097 us; speedup vs baseline: 1.3198x; 1.3198x over previous
//
#include <hip/hip_runtime.h>

#define NNODE 10000
#define NEDGE 160000
#define DD 256

using f32x4  = __attribute__((ext_vector_type(4))) float;
using bf16x8 = __attribute__((ext_vector_type(8))) short;
using u32x4  = __attribute__((ext_vector_type(4))) unsigned;

__device__ inline short f2bf(float f) {
  unsigned u = __float_as_uint(f);
  unsigned r = (u + 0x7fffu + ((u >> 16) & 1u)) >> 16;
  return (short)(unsigned short)r;
}

__device__ inline float bf2f(short s) {
  return __uint_as_float(((unsigned)(unsigned short)s) << 16);
}

__device__ inline unsigned pkbf(float a, float b) {
  unsigned r;
  asm("v_cvt_pk_bf16_f32 %0, %1, %2" : "=v"(r) : "v"(a), "v"(b));
  return r;
}

__global__ void cast_x_kernel(const float* __restrict__ x, short* __restrict__ xb, int total) {
  int i = blockIdx.x * 256 + threadIdx.x;
  if (i < total) xb[i] = f2bf(x[i]);
}

// generic pack w[K][N] (f32) -> p[(k>>3)][n][k&7] (bf16)
__global__ void pack_w_kernel(const float* __restrict__ w, short* __restrict__ p, int K, int N) {
  int idx = blockIdx.x * 256 + threadIdx.x;
  if (idx >= K * N) return;
  int k = idx / N, n = idx - k * N;
  p[(size_t)(k >> 3) * N * 8 + (size_t)n * 8 + (k & 7)] = f2bf(w[idx]);
}

// e_w1 [768][512] split: rows 0..255 -> w1abp half0, 256..511 -> w1abp half1 (N=1024),
// rows 512..767 -> w1cp (N=512). Same MFMA-native (k>>3, n, k&7) layout.
__global__ void pack_ew1_kernel(const float* __restrict__ w, short* __restrict__ w1abp,
                                short* __restrict__ w1cp) {
  int idx = blockIdx.x * 256 + threadIdx.x;
  if (idx >= 768 * 512) return;
  int k = idx >> 9, n = idx & 511;
  short v = f2bf(w[idx]);
  if (k < 256) {
    w1abp[(size_t)(k >> 3) * 1024 * 8 + (size_t)n * 8 + (k & 7)] = v;
  } else if (k < 512) {
    int kk = k - 256;
    w1abp[(size_t)(kk >> 3) * 1024 * 8 + (size_t)(512 + n) * 8 + (kk & 7)] = v;
  } else {
    int kk = k - 512;
    w1cp[(size_t)(kk >> 3) * 512 * 8 + (size_t)n * 8 + (kk & 7)] = v;
  }
}

// ---------------- CSR build ----------------
__global__ void hist_kernel(const int* __restrict__ ei, int* __restrict__ deg) {
  int e = blockIdx.x * 256 + threadIdx.x;
  if (e < NEDGE) {
    int j = ei[NEDGE + e]; j = min(max(j, 0), NNODE - 1);
    atomicAdd(&deg[j], 1);
  }
}

__global__ void scan_kernel(const int* __restrict__ deg, int* __restrict__ row_start) {
  __shared__ int part[256];
  int t = threadIdx.x;
  const int CH = 40;
  int base = t * CH;
  int s = 0;
  for (int i = 0; i < CH; i++) {
    int idx = base + i;
    s += (idx < NNODE) ? deg[idx] : 0;
  }
  part[t] = s;
  __syncthreads();
  for (int off = 1; off < 256; off <<= 1) {
    int v = (t >= off) ? part[t - off] : 0;
    __syncthreads();
    part[t] += v;
    __syncthreads();
  }
  int run = (t == 0) ? 0 : part[t - 1];
  for (int i = 0; i < CH; i++) {
    int idx = base + i;
    if (idx < NNODE) { row_start[idx] = run; run += deg[idx]; }
  }
  if (t == 255) row_start[NNODE] = part[255];
}

__global__ void scatter_kernel(const int* __restrict__ ei, const int* __restrict__ row_start,
                               int* __restrict__ cursor, int* __restrict__ csr) {
  int e = blockIdx.x * 256 + threadIdx.x;
  if (e < NEDGE) {
    int j = ei[NEDGE + e]; j = min(max(j, 0), NNODE - 1);
    int p = atomicAdd(&cursor[j], 1);
    csr[row_start[j] + p] = e;
  }
}

__global__ __launch_bounds__(256) void agg_kernel(const float* __restrict__ out_e,
                                                  const int* __restrict__ row_start,
                                                  const int* __restrict__ csr,
                                                  short* __restrict__ aggb) {
  int node = blockIdx.x * 4 + (threadIdx.x >> 6);
  int lane = threadIdx.x & 63;
  if (node >= NNODE) return;
  int rs = row_start[node], re = row_start[node + 1];
  float4 acc = {0.f, 0.f, 0.f, 0.f};
  for (int k = rs; k < re; k++) {
    int eid = csr[k];
    float4 v = *(const float4*)(out_e + (size_t)eid * DD + lane * 4);
    acc.x += v.x; acc.y += v.y; acc.z += v.z; acc.w += v.w;
  }
  short4 o;
  o.x = f2bf(acc.x); o.y = f2bf(acc.y); o.z = f2bf(acc.z); o.w = f2bf(acc.w);
  *(short4*)(aggb + (size_t)node * DD + lane * 4) = o;
}

// ---------------- precomp: Pab = x @ [W1a | W1b], packed-fragment bf16 ----------------
// grid (157, 2): blockIdx.y = half h. Output row layout: pab[row][h*512 + llo*32 + wid*8 + nf]
// i.e. element for logical col c = wid*128+nf*16+llo stored at (c&15)*32 + (c>>4).
__global__ __launch_bounds__(256, 2)
void precomp_pab(const short* __restrict__ xb, const short* __restrict__ w1abp,
                 short* __restrict__ pab) {
  __shared__ __align__(16) short abuf[2048 * 8];  // 32 KB: [64 rows][32 segs of 8] swizzled

  const int tid  = threadIdx.x;
  const int lane = tid & 63;
  const int wid  = tid >> 6;
  const int lhi  = lane >> 4;
  const int llo  = lane & 15;
  const int swz  = llo & 7;
  const int m0   = blockIdx.x * 64;
  const int h    = blockIdx.y;

  // stage A (xb rows m0..m0+63, K=256) swizzled via global_load_lds
  #pragma unroll
  for (int q = 0; q < 8; q++) {
    int S = wid * 512 + q * 64 + lane;
    int row = S >> 5;
    int segp = S & 31;
    int seg = segp ^ (row & 7);
    int rowg = min(m0 + row, NNODE - 1);
    __builtin_amdgcn_global_load_lds(
        (const int*)((const char*)xb + (size_t)rowg * 512 + seg * 16),
        (int*)(abuf + (size_t)(wid * 512 + q * 64) * 8), 16, 0, 0);
  }
  __syncthreads();

  f32x4 acc1[4][8] = {};
  const bf16x8* bp1 = (const bf16x8*)w1abp;
  #pragma unroll
  for (int kk = 0; kk < 256; kk += 32) {
    const int ks = kk >> 3;
    bf16x8 a[4];
    #pragma unroll
    for (int mf = 0; mf < 4; mf++)
      a[mf] = *(const bf16x8*)(abuf + ((mf * 16 + llo) * 32 + ((ks + lhi) ^ swz)) * 8);
    const bf16x8* bb = bp1 + (size_t)(ks + lhi) * 1024 + h * 512 + wid * 128 + llo;
    #pragma unroll
    for (int nf = 0; nf < 8; nf++) {
      bf16x8 b = bb[nf * 16];
      #pragma unroll
      for (int mf = 0; mf < 4; mf++)
        acc1[mf][nf] = __builtin_amdgcn_mfma_f32_16x16x32_bf16(a[mf], b, acc1[mf][nf], 0, 0, 0);
    }
  }

  #pragma unroll
  for (int mf = 0; mf < 4; mf++) {
    #pragma unroll
    for (int r = 0; r < 4; r++) {
      int row = m0 + mf * 16 + lhi * 4 + r;
      if (row < NNODE) {
        u32x4 wv = { pkbf(acc1[mf][0][r], acc1[mf][1][r]),
                     pkbf(acc1[mf][2][r], acc1[mf][3][r]),
                     pkbf(acc1[mf][4][r], acc1[mf][5][r]),
                     pkbf(acc1[mf][6][r], acc1[mf][7][r]) };
        *(u32x4*)(pab + (size_t)row * 1024 + h * 512 + llo * 32 + wid * 8) = wv;
      }
    }
  }
}

// ---------------- edge kernel ----------------
// hidden = relu(ea@W1c + Pab[i] + Pab[j] + b1); out_e = ea + LN(hidden@W2 + b2)
// No gathered GEMM operands: ea staged sequential/coalesced; Pab added post-GEMM (L3-hot).
__global__ __launch_bounds__(256, 2)
void fused_edge(const int* __restrict__ ei,
                const float* __restrict__ ea,
                const short* __restrict__ pab,
                const short* __restrict__ w1cp,
                const float* __restrict__ b1,
                const short* __restrict__ w2p,
                const float* __restrict__ b2,
                const float* __restrict__ gam,
                const float* __restrict__ bet,
                float* __restrict__ out)
{
  __shared__ __align__(16) short hid[64 * 512];  // 64 KB; first 32 KB doubles as ea stage buf
  __shared__ int idxi[64], idxj[64];
  __shared__ float pS[256], pQ[256];

  short* abuf = hid;  // [64 rows][32 segs of 8] swizzled (union with hid)

  const int tid  = threadIdx.x;
  const int lane = tid & 63;
  const int wid  = tid >> 6;
  const int lhi  = lane >> 4;
  const int llo  = lane & 15;
  const int swz  = llo & 7;
  const int m0   = blockIdx.x * 64;

  if (tid < 64) {
    int a = ei[m0 + tid];
    int b = ei[NEDGE + m0 + tid];
    idxi[tid] = min(max(a, 0), NNODE - 1);
    idxj[tid] = min(max(b, 0), NNODE - 1);
  }

  // stage ea tile (64 x 256 f32 -> bf16, swizzled): coalesced sequential rows
  #pragma unroll
  for (int q = 0; q < 8; q++) {
    int S = q * 256 + tid;
    int row = S >> 5;
    int segp = S & 31;
    int seg = segp ^ (row & 7);
    const float* src = ea + (size_t)(m0 + row) * 256 + seg * 8;
    float4 u0 = *(const float4*)src;
    float4 u1 = *(const float4*)(src + 4);
    u32x4 qv = { pkbf(u0.x, u0.y), pkbf(u0.z, u0.w), pkbf(u1.x, u1.y), pkbf(u1.z, u1.w) };
    *(u32x4*)(abuf + (size_t)S * 8) = qv;
  }
  __syncthreads();

  // ---------------- GEMM_c: [64 x 256] @ [256 x 512] ----------------
  f32x4 acc1[4][8] = {};
  const bf16x8* bp1 = (const bf16x8*)w1cp;
  #pragma unroll
  for (int kk = 0; kk < 256; kk += 32) {
    const int ks = kk >> 3;
    bf16x8 a[4];
    #pragma unroll
    for (int mf = 0; mf < 4; mf++)
      a[mf] = *(const bf16x8*)(abuf + ((mf * 16 + llo) * 32 + ((ks + lhi) ^ swz)) * 8);
    const bf16x8* bb = bp1 + (size_t)(ks + lhi) * 512 + wid * 128 + llo;
    #pragma unroll
    for (int nf = 0; nf < 8; nf++) {
      bf16x8 b = bb[nf * 16];
      #pragma unroll
      for (int mf = 0; mf < 4; mf++)
        acc1[mf][nf] = __builtin_amdgcn_mfma_f32_16x16x32_bf16(a[mf], b, acc1[mf][nf], 0, 0, 0);
    }
  }

  // ---------------- add gathered Pab rows (packed-fragment layout) ----------------
  #pragma unroll
  for (int mf = 0; mf < 4; mf++) {
    #pragma unroll
    for (int r = 0; r < 4; r++) {
      int row = mf * 16 + lhi * 4 + r;
      int gi = idxi[row], gj = idxj[row];
      bf16x8 pa = *(const bf16x8*)(pab + (size_t)gi * 1024 + llo * 32 + wid * 8);
      bf16x8 pb = *(const bf16x8*)(pab + (size_t)gj * 1024 + 512 + llo * 32 + wid * 8);
      #pragma unroll
      for (int nf = 0; nf < 8; nf++)
        acc1[mf][nf][r] += bf2f(pa[nf]) + bf2f(pb[nf]);
    }
  }
  __syncthreads();  // all GEMM_c LDS reads done before hid overwrites abuf

  // ---------------- bias + relu -> hid (XOR-swizzled, K=512) ----------------
  #pragma unroll
  for (int nf = 0; nf < 8; nf++) {
    int col = wid * 128 + nf * 16 + llo;
    float bb = b1[col];
    int cs = col >> 3, cl = col & 7;
    #pragma unroll
    for (int mf = 0; mf < 4; mf++) {
      #pragma unroll
      for (int r = 0; r < 4; r++) {
        int row = mf * 16 + lhi * 4 + r;
        float v = acc1[mf][nf][r] + bb;
        v = v > 0.f ? v : 0.f;
        hid[row * 512 + ((cs ^ (row & 7)) * 8) + cl] = f2bf(v);
      }
    }
  }
  __syncthreads();

  // ---------------- GEMM2: [64 x 512] @ [512 x 256] ----------------
  f32x4 acc2[4][4] = {};
  const bf16x8* bp2 = (const bf16x8*)w2p;
  const int bcol2 = wid * 64 + llo;
  #pragma unroll
  for (int kk = 0; kk < 512; kk += 32) {
    const int ks = kk >> 3;
    bf16x8 a[4];
    #pragma unroll
    for (int mf = 0; mf < 4; mf++) {
      int row = mf * 16 + llo;
      a[mf] = *(const bf16x8*)(hid + row * 512 + (((ks + lhi) ^ swz) * 8));
    }
    const bf16x8* bb = bp2 + (size_t)(ks + lhi) * 256 + bcol2;
    #pragma unroll
    for (int nf = 0; nf < 4; nf++) {
      bf16x8 b = bb[nf * 16];
      #pragma unroll
      for (int mf = 0; mf < 4; mf++)
        acc2[mf][nf] = __builtin_amdgcn_mfma_f32_16x16x32_bf16(a[mf], b, acc2[mf][nf], 0, 0, 0);
    }
  }

  // ---------------- LayerNorm in registers ----------------
  float bb2[4], gg[4], be[4];
  #pragma unroll
  for (int nf = 0; nf < 4; nf++) {
    int col = bcol2 + nf * 16;
    bb2[nf] = b2[col]; gg[nf] = gam[col]; be[nf] = bet[col];
  }
  #pragma unroll
  for (int mf = 0; mf < 4; mf++)
    #pragma unroll
    for (int nf = 0; nf < 4; nf++)
      #pragma unroll
      for (int r = 0; r < 4; r++)
        acc2[mf][nf][r] += bb2[nf];

  float S[4][4], Q[4][4];
  #pragma unroll
  for (int mf = 0; mf < 4; mf++) {
    #pragma unroll
    for (int r = 0; r < 4; r++) {
      float s = 0.f, q = 0.f;
      #pragma unroll
      for (int nf = 0; nf < 4; nf++) {
        float v = acc2[mf][nf][r];
        s += v; q += v * v;
      }
      S[mf][r] = s; Q[mf][r] = q;
    }
  }
  #pragma unroll
  for (int m = 1; m <= 8; m <<= 1) {
    #pragma unroll
    for (int mf = 0; mf < 4; mf++)
      #pragma unroll
      for (int r = 0; r < 4; r++) {
        S[mf][r] += __shfl_xor(S[mf][r], m);
        Q[mf][r] += __shfl_xor(Q[mf][r], m);
      }
  }
  if (llo == 0) {
    #pragma unroll
    for (int mf = 0; mf < 4; mf++)
      #pragma unroll
      for (int r = 0; r < 4; r++) {
        int row = mf * 16 + lhi * 4 + r;
        pS[wid * 64 + row] = S[mf][r];
        pQ[wid * 64 + row] = Q[mf][r];
      }
  }
  __syncthreads();

  float mu[4][4], rsv[4][4];
  #pragma unroll
  for (int mf = 0; mf < 4; mf++) {
    #pragma unroll
    for (int r = 0; r < 4; r++) {
      int row = mf * 16 + lhi * 4 + r;
      float s = pS[row] + pS[64 + row] + pS[128 + row] + pS[192 + row];
      float q = pQ[row] + pQ[64 + row] + pQ[128 + row] + pQ[192 + row];
      float m_ = s * (1.f / 256.f);
      mu[mf][r]  = m_;
      rsv[mf][r] = rsqrtf(q * (1.f / 256.f) - m_ * m_ + 1e-5f);
    }
  }

  #pragma unroll
  for (int mf = 0; mf < 4; mf++) {
    #pragma unroll
    for (int r = 0; r < 4; r++) {
      int grow = m0 + mf * 16 + lhi * 4 + r;
      const float* rp = ea  + (size_t)grow * DD + bcol2;
      float*       op = out + (size_t)grow * DD + bcol2;
      #pragma unroll
      for (int nf = 0; nf < 4; nf++) {
        float v = (acc2[mf][nf][r] - mu[mf][r]) * rsv[mf][r] * gg[nf] + be[nf] + rp[nf * 16];
        op[nf * 16] = v;
      }
    }
  }
}

// ---------------- node kernel (R3-proven structure) ----------------
__global__ __launch_bounds__(256, 2)
void fused_node(const float* __restrict__ x,
                const short* __restrict__ xb,
                const short* __restrict__ aggb,
                const short* __restrict__ w1p,
                const float* __restrict__ b1,
                const short* __restrict__ w2p,
                const float* __restrict__ b2,
                const float* __restrict__ gam,
                const float* __restrict__ bet,
                float* __restrict__ out)
{
  constexpr int HP = 520;
  __shared__ __align__(16) short hid[64 * HP];
  __shared__ float pS[4][64], pQ[4][64];

  const int tid  = threadIdx.x;
  const int lane = tid & 63;
  const int wid  = tid >> 6;
  const int m0   = blockIdx.x * 64;
  const int lhi  = lane >> 4;
  const int llo  = lane & 15;

  const short* pI[4]; const short* pJ[4];
  #pragma unroll
  for (int mf = 0; mf < 4; mf++) {
    int rr = min(m0 + mf * 16 + llo, NNODE - 1);
    pI[mf] = xb + (size_t)rr * DD;
    pJ[mf] = aggb + (size_t)rr * DD;
  }

  f32x4 acc1[4][8] = {};
  const bf16x8* bp1 = (const bf16x8*)w1p;
  const int bcol1 = wid * 128 + llo;

  #pragma unroll
  for (int s = 0; s < 8; s++) {
    #pragma unroll
    for (int kk = 0; kk < 64; kk += 32) {
      const int ko = s * 64 + kk + lhi * 8;
      bf16x8 a[4];
      #pragma unroll
      for (int mf = 0; mf < 4; mf++) {
        if (s < 4) a[mf] = *(const bf16x8*)(pI[mf] + ko);
        else       a[mf] = *(const bf16x8*)(pJ[mf] + (ko - 256));
      }
      const bf16x8* bb = bp1 + (size_t)(s * 8 + (kk >> 3) + lhi) * 512 + bcol1;
      #pragma unroll
      for (int nf = 0; nf < 8; nf++) {
        bf16x8 b = bb[nf * 16];
        #pragma unroll
        for (int mf = 0; mf < 4; mf++)
          acc1[mf][nf] = __builtin_amdgcn_mfma_f32_16x16x32_bf16(a[mf], b, acc1[mf][nf], 0, 0, 0);
      }
    }
  }

  #pragma unroll
  for (int nf = 0; nf < 8; nf++) {
    int col = wid * 128 + nf * 16 + llo;
    float bb = b1[col];
    #pragma unroll
    for (int mf = 0; mf < 4; mf++) {
      #pragma unroll
      for (int r = 0; r < 4; r++) {
        float v = acc1[mf][nf][r] + bb;
        v = v > 0.f ? v : 0.f;
        hid[(mf * 16 + lhi * 4 + r) * HP + col] = f2bf(v);
      }
    }
  }
  __syncthreads();

  f32x4 acc2[4][4] = {};
  const bf16x8* bp2 = (const bf16x8*)w2p;
  const int bcol2 = wid * 64 + llo;
  #pragma unroll
  for (int kk = 0; kk < 512; kk += 32) {
    bf16x8 a[4];
    #pragma unroll
    for (int mf = 0; mf < 4; mf++)
      a[mf] = *(const bf16x8*)(hid + (mf * 16 + llo) * HP + kk + lhi * 8);
    const bf16x8* bb = bp2 + (size_t)((kk >> 3) + lhi) * 256 + bcol2;
    #pragma unroll
    for (int nf = 0; nf < 4; nf++) {
      bf16x8 b = bb[nf * 16];
      #pragma unroll
      for (int mf = 0; mf < 4; mf++)
        acc2[mf][nf] = __builtin_amdgcn_mfma_f32_16x16x32_bf16(a[mf], b, acc2[mf][nf], 0, 0, 0);
    }
  }

  float bb2[4], gg[4], be[4];
  #pragma unroll
  for (int nf = 0; nf < 4; nf++) {
    int col = bcol2 + nf * 16;
    bb2[nf] = b2[col]; gg[nf] = gam[col]; be[nf] = bet[col];
  }
  #pragma unroll
  for (int mf = 0; mf < 4; mf++)
    #pragma unroll
    for (int nf = 0; nf < 4; nf++)
      #pragma unroll
      for (int r = 0; r < 4; r++)
        acc2[mf][nf][r] += bb2[nf];

  float S[4][4], Q[4][4];
  #pragma unroll
  for (int mf = 0; mf < 4; mf++) {
    #pragma unroll
    for (int r = 0; r < 4; r++) {
      float s = 0.f, q = 0.f;
      #pragma unroll
      for (int nf = 0; nf < 4; nf++) {
        float v = acc2[mf][nf][r];
        s += v; q += v * v;
      }
      S[mf][r] = s; Q[mf][r] = q;
    }
  }
  #pragma unroll
  for (int m = 1; m <= 8; m <<= 1) {
    #pragma unroll
    for (int mf = 0; mf < 4; mf++)
      #pragma unroll
      for (int r = 0; r < 4; r++) {
        S[mf][r] += __shfl_xor(S[mf][r], m);
        Q[mf][r] += __shfl_xor(Q[mf][r], m);
      }
  }
  if (llo == 0) {
    #pragma unroll
    for (int mf = 0; mf < 4; mf++)
      #pragma unroll
      for (int r = 0; r < 4; r++) {
        int row = mf * 16 + lhi * 4 + r;
        pS[wid][row] = S[mf][r];
        pQ[wid][row] = Q[mf][r];
      }
  }
  __syncthreads();

  float mu[4][4], rsv[4][4];
  #pragma unroll
  for (int mf = 0; mf < 4; mf++) {
    #pragma unroll
    for (int r = 0; r < 4; r++) {
      int row = mf * 16 + lhi * 4 + r;
      float s = pS[0][row] + pS[1][row] + pS[2][row] + pS[3][row];
      float q = pQ[0][row] + pQ[1][row] + pQ[2][row] + pQ[3][row];
      float m_ = s * (1.f / 256.f);
      mu[mf][r]  = m_;
      rsv[mf][r] = rsqrtf(q * (1.f / 256.f) - m_ * m_ + 1e-5f);
    }
  }

  #pragma unroll
  for (int mf = 0; mf < 4; mf++) {
    #pragma unroll
    for (int r = 0; r < 4; r++) {
      int grow = m0 + mf * 16 + lhi * 4 + r;
      if (grow >= NNODE) continue;
      const float* rp = x   + (size_t)grow * DD + bcol2;
      float*       op = out + (size_t)grow * DD + bcol2;
      #pragma unroll
      for (int nf = 0; nf < 4; nf++) {
        float v = (acc2[mf][nf][r] - mu[mf][r]) * rsv[mf][r] * gg[nf] + be[nf] + rp[nf * 16];
        op[nf * 16] = v;
      }
    }
  }
}

extern "C" void kernel_launch(void* const* d_in, const int* in_sizes, int n_in,
                              void* d_out, int out_size, void* d_ws, size_t ws_size,
                              hipStream_t stream) {
  const float* x      = (const float*)d_in[0];
  const int*   ei     = (const int*)  d_in[1];
  const float* ea     = (const float*)d_in[2];
  const float* e_w1   = (const float*)d_in[3];
  const float* e_b1   = (const float*)d_in[4];
  const float* e_w2   = (const float*)d_in[5];
  const float* e_b2   = (const float*)d_in[6];
  const float* e_g    = (const float*)d_in[7];
  const float* e_beta = (const float*)d_in[8];
  const float* n_w1   = (const float*)d_in[9];
  const float* n_b1   = (const float*)d_in[10];
  const float* n_w2   = (const float*)d_in[11];
  const float* n_b2   = (const float*)d_in[12];
  const float* n_g    = (const float*)d_in[13];
  const float* n_beta = (const float*)d_in[14];

  float* out_x = (float*)d_out;
  float* out_e = (float*)d_out + (size_t)NNODE * DD;

  char* w = (char*)d_ws;
  short* xb    = (short*)(w);                   //  5,120,000 B
  short* aggb  = (short*)(w + 5120000);         //  5,120,000 B
  short* pab   = (short*)(w + 10240000);        // 20,480,000 B
  short* w1abp = (short*)(w + 30720000);        //    524,288 B
  short* w1cp  = (short*)(w + 31244288);        //    262,144 B
  short* ew2p  = (short*)(w + 31506432);        //    262,144 B
  short* nw1p  = (short*)(w + 31768576);        //    524,288 B
  short* nw2p  = (short*)(w + 32292864);        //    262,144 B
  int*   deg   = (int*)  (w + 32555008);        //     40,960 B
  int*   cur   = (int*)  (w + 32595968);        //     40,960 B
  int*   rs    = (int*)  (w + 32636928);        //     40,976 B
  int*   csr   = (int*)  (w + 32677904);        //    640,000 B  -> ~33.3 MB total

  hipMemsetAsync(deg, 0, 81920, stream);  // deg + cursor

  cast_x_kernel<<<(NNODE * DD + 255) / 256, 256, 0, stream>>>(x, xb, NNODE * DD);
  pack_ew1_kernel<<<(768 * 512 + 255) / 256, 256, 0, stream>>>(e_w1, w1abp, w1cp);
  pack_w_kernel<<<(512 * 512 + 255) / 256, 256, 0, stream>>>(n_w1, nw1p, 512, 512);
  pack_w_kernel<<<(512 * 256 + 255) / 256, 256, 0, stream>>>(e_w2, ew2p, 512, 256);
  pack_w_kernel<<<(512 * 256 + 255) / 256, 256, 0, stream>>>(n_w2, nw2p, 512, 256);

  hist_kernel<<<(NEDGE + 255) / 256, 256, 0, stream>>>(ei, deg);
  scan_kernel<<<1, 256, 0, stream>>>(deg, rs);
  scatter_kernel<<<(NEDGE + 255) / 256, 256, 0, stream>>>(ei, rs, cur, csr);

  precomp_pab<<<dim3((NNODE + 63) / 64, 2), 256, 0, stream>>>(xb, w1abp, pab);

  fused_edge<<<NEDGE / 64, 256, 0, stream>>>(ei, ea, pab, w1cp, e_b1,
                                             ew2p, e_b2, e_g, e_beta, out_e);
  agg_kernel<<<(NNODE + 3) / 4, 256, 0, stream>>>(out_e, rs, csr, aggb);
  fused_node<<<(NNODE + 63) / 64, 256, 0, stream>>>(x, xb, aggb, nw1p, n_b1,
                                                    nw2p, n_b2, n_g, n_beta, out_x);
}

// Round 7
// 529.002 us; speedup vs baseline: 1.3275x; 1.0059x over previous
//
#include <hip/hip_runtime.h>

#define NNODE 10000
#define NEDGE 160000
#define DD 256

using f32x4  = __attribute__((ext_vector_type(4))) float;
using bf16x8 = __attribute__((ext_vector_type(8))) short;
using u32x4  = __attribute__((ext_vector_type(4))) unsigned;

__device__ inline short f2bf(float f) {
  unsigned u = __float_as_uint(f);
  unsigned r = (u + 0x7fffu + ((u >> 16) & 1u)) >> 16;
  return (short)(unsigned short)r;
}

__device__ inline float bf2f(short s) {
  return __uint_as_float(((unsigned)(unsigned short)s) << 16);
}

__device__ inline unsigned pkbf(float a, float b) {
  unsigned r;
  asm("v_cvt_pk_bf16_f32 %0, %1, %2" : "=v"(r) : "v"(a), "v"(b));
  return r;
}

__global__ void cast_x_kernel(const float* __restrict__ x, short* __restrict__ xb, int total) {
  int i = blockIdx.x * 256 + threadIdx.x;
  if (i < total) xb[i] = f2bf(x[i]);
}

// generic pack w[K][N] (f32) -> p[(k>>3)][n][k&7] (bf16)
__global__ void pack_w_kernel(const float* __restrict__ w, short* __restrict__ p, int K, int N) {
  int idx = blockIdx.x * 256 + threadIdx.x;
  if (idx >= K * N) return;
  int k = idx / N, n = idx - k * N;
  p[(size_t)(k >> 3) * N * 8 + (size_t)n * 8 + (k & 7)] = f2bf(w[idx]);
}

// e_w1 [768][512] split: rows 0..255 -> w1abp half0, 256..511 -> w1abp half1 (N=1024),
// rows 512..767 -> w1cp (N=512). Same MFMA-native (k>>3, n, k&7) layout.
__global__ void pack_ew1_kernel(const float* __restrict__ w, short* __restrict__ w1abp,
                                short* __restrict__ w1cp) {
  int idx = blockIdx.x * 256 + threadIdx.x;
  if (idx >= 768 * 512) return;
  int k = idx >> 9, n = idx & 511;
  short v = f2bf(w[idx]);
  if (k < 256) {
    w1abp[(size_t)(k >> 3) * 1024 * 8 + (size_t)n * 8 + (k & 7)] = v;
  } else if (k < 512) {
    int kk = k - 256;
    w1abp[(size_t)(kk >> 3) * 1024 * 8 + (size_t)(512 + n) * 8 + (kk & 7)] = v;
  } else {
    int kk = k - 512;
    w1cp[(size_t)(kk >> 3) * 512 * 8 + (size_t)n * 8 + (kk & 7)] = v;
  }
}

// ---------------- CSR build ----------------
__global__ void hist_kernel(const int* __restrict__ ei, int* __restrict__ deg) {
  int e = blockIdx.x * 256 + threadIdx.x;
  if (e < NEDGE) {
    int j = ei[NEDGE + e]; j = min(max(j, 0), NNODE - 1);
    atomicAdd(&deg[j], 1);
  }
}

__global__ void scan_kernel(const int* __restrict__ deg, int* __restrict__ row_start) {
  __shared__ int part[256];
  int t = threadIdx.x;
  const int CH = 40;
  int base = t * CH;
  int s = 0;
  for (int i = 0; i < CH; i++) {
    int idx = base + i;
    s += (idx < NNODE) ? deg[idx] : 0;
  }
  part[t] = s;
  __syncthreads();
  for (int off = 1; off < 256; off <<= 1) {
    int v = (t >= off) ? part[t - off] : 0;
    __syncthreads();
    part[t] += v;
    __syncthreads();
  }
  int run = (t == 0) ? 0 : part[t - 1];
  for (int i = 0; i < CH; i++) {
    int idx = base + i;
    if (idx < NNODE) { row_start[idx] = run; run += deg[idx]; }
  }
  if (t == 255) row_start[NNODE] = part[255];
}

__global__ void scatter_kernel(const int* __restrict__ ei, const int* __restrict__ row_start,
                               int* __restrict__ cursor, int* __restrict__ csr) {
  int e = blockIdx.x * 256 + threadIdx.x;
  if (e < NEDGE) {
    int j = ei[NEDGE + e]; j = min(max(j, 0), NNODE - 1);
    int p = atomicAdd(&cursor[j], 1);
    csr[row_start[j] + p] = e;
  }
}

__global__ __launch_bounds__(256) void agg_kernel(const float* __restrict__ out_e,
                                                  const int* __restrict__ row_start,
                                                  const int* __restrict__ csr,
                                                  short* __restrict__ aggb) {
  int node = blockIdx.x * 4 + (threadIdx.x >> 6);
  int lane = threadIdx.x & 63;
  if (node >= NNODE) return;
  int rs = row_start[node], re = row_start[node + 1];
  float4 acc = {0.f, 0.f, 0.f, 0.f};
  for (int k = rs; k < re; k++) {
    int eid = csr[k];
    float4 v = *(const float4*)(out_e + (size_t)eid * DD + lane * 4);
    acc.x += v.x; acc.y += v.y; acc.z += v.z; acc.w += v.w;
  }
  short4 o;
  o.x = f2bf(acc.x); o.y = f2bf(acc.y); o.z = f2bf(acc.z); o.w = f2bf(acc.w);
  *(short4*)(aggb + (size_t)node * DD + lane * 4) = o;
}

// ---------------- precomp: Pab = x @ [W1a | W1b], packed-fragment bf16 ----------------
// Output row layout: pab[row][h*512 + llo*32 + wid*8 + nf]
__global__ __launch_bounds__(256, 2)
void precomp_pab(const short* __restrict__ xb, const short* __restrict__ w1abp,
                 short* __restrict__ pab) {
  __shared__ __align__(16) short abuf[2048 * 8];  // 32 KB: [64 rows][32 segs of 8] swizzled

  const int tid  = threadIdx.x;
  const int lane = tid & 63;
  const int wid  = tid >> 6;
  const int lhi  = lane >> 4;
  const int llo  = lane & 15;
  const int swz  = llo & 7;
  const int m0   = blockIdx.x * 64;
  const int h    = blockIdx.y;

  #pragma unroll
  for (int q = 0; q < 8; q++) {
    int S = wid * 512 + q * 64 + lane;
    int row = S >> 5;
    int segp = S & 31;
    int seg = segp ^ (row & 7);
    int rowg = min(m0 + row, NNODE - 1);
    __builtin_amdgcn_global_load_lds(
        (const int*)((const char*)xb + (size_t)rowg * 512 + seg * 16),
        (int*)(abuf + (size_t)(wid * 512 + q * 64) * 8), 16, 0, 0);
  }
  __syncthreads();

  f32x4 acc1[4][8] = {};
  const bf16x8* bp1 = (const bf16x8*)w1abp;
  #pragma unroll
  for (int kk = 0; kk < 256; kk += 32) {
    const int ks = kk >> 3;
    bf16x8 a[4];
    #pragma unroll
    for (int mf = 0; mf < 4; mf++)
      a[mf] = *(const bf16x8*)(abuf + ((mf * 16 + llo) * 32 + ((ks + lhi) ^ swz)) * 8);
    const bf16x8* bb = bp1 + (size_t)(ks + lhi) * 1024 + h * 512 + wid * 128 + llo;
    #pragma unroll
    for (int nf = 0; nf < 8; nf++) {
      bf16x8 b = bb[nf * 16];
      #pragma unroll
      for (int mf = 0; mf < 4; mf++)
        acc1[mf][nf] = __builtin_amdgcn_mfma_f32_16x16x32_bf16(a[mf], b, acc1[mf][nf], 0, 0, 0);
    }
  }

  #pragma unroll
  for (int mf = 0; mf < 4; mf++) {
    #pragma unroll
    for (int r = 0; r < 4; r++) {
      int row = m0 + mf * 16 + lhi * 4 + r;
      if (row < NNODE) {
        u32x4 wv = { pkbf(acc1[mf][0][r], acc1[mf][1][r]),
                     pkbf(acc1[mf][2][r], acc1[mf][3][r]),
                     pkbf(acc1[mf][4][r], acc1[mf][5][r]),
                     pkbf(acc1[mf][6][r], acc1[mf][7][r]) };
        *(u32x4*)(pab + (size_t)row * 1024 + h * 512 + llo * 32 + wid * 8) = wv;
      }
    }
  }
}

// ---------------- edge kernel (CSR-ordered) ----------------
// Block b processes edges csr[64b..64b+63] (grouped by destination j):
// Pab[j] reads are L2-local (~4 unique j per block), halving random-gather volume.
// hidden = relu(ea@W1c + Pab[i] + Pab[j] + b1); out_e[eid] = ea[eid] + LN(hidden@W2 + b2)
__global__ __launch_bounds__(256, 2)
void fused_edge(const int* __restrict__ ei,
                const int* __restrict__ csr,
                const float* __restrict__ ea,
                const short* __restrict__ pab,
                const short* __restrict__ w1cp,
                const float* __restrict__ b1,
                const short* __restrict__ w2p,
                const float* __restrict__ b2,
                const float* __restrict__ gam,
                const float* __restrict__ bet,
                float* __restrict__ out)
{
  __shared__ __align__(16) short hid[64 * 512];  // 64 KB; first 32 KB doubles as ea stage buf
  __shared__ int eidx[64], idxi[64], idxj[64];
  __shared__ float pS[256], pQ[256];

  short* abuf = hid;  // [64 rows][32 segs of 8] swizzled (union with hid)

  const int tid  = threadIdx.x;
  const int lane = tid & 63;
  const int wid  = tid >> 6;
  const int lhi  = lane >> 4;
  const int llo  = lane & 15;
  const int swz  = llo & 7;
  const int m0   = blockIdx.x * 64;

  if (tid < 64) {
    int e = csr[m0 + tid];
    eidx[tid] = e;
    int a = ei[e];
    int b = ei[NEDGE + e];
    idxi[tid] = min(max(a, 0), NNODE - 1);
    idxj[tid] = min(max(b, 0), NNODE - 1);
  }
  __syncthreads();

  // stage ea tile (64 gathered rows, f32 -> bf16, swizzled): 1KB-contiguous per row
  #pragma unroll
  for (int q = 0; q < 8; q++) {
    int S = q * 256 + tid;
    int row = S >> 5;
    int segp = S & 31;
    int seg = segp ^ (row & 7);
    const float* src = ea + (size_t)eidx[row] * 256 + seg * 8;
    float4 u0 = *(const float4*)src;
    float4 u1 = *(const float4*)(src + 4);
    u32x4 qv = { pkbf(u0.x, u0.y), pkbf(u0.z, u0.w), pkbf(u1.x, u1.y), pkbf(u1.z, u1.w) };
    *(u32x4*)(abuf + (size_t)S * 8) = qv;
  }
  __syncthreads();

  // ---------------- GEMM_c: [64 x 256] @ [256 x 512] ----------------
  f32x4 acc1[4][8] = {};
  const bf16x8* bp1 = (const bf16x8*)w1cp;
  #pragma unroll
  for (int kk = 0; kk < 256; kk += 32) {
    const int ks = kk >> 3;
    bf16x8 a[4];
    #pragma unroll
    for (int mf = 0; mf < 4; mf++)
      a[mf] = *(const bf16x8*)(abuf + ((mf * 16 + llo) * 32 + ((ks + lhi) ^ swz)) * 8);
    const bf16x8* bb = bp1 + (size_t)(ks + lhi) * 512 + wid * 128 + llo;
    #pragma unroll
    for (int nf = 0; nf < 8; nf++) {
      bf16x8 b = bb[nf * 16];
      #pragma unroll
      for (int mf = 0; mf < 4; mf++)
        acc1[mf][nf] = __builtin_amdgcn_mfma_f32_16x16x32_bf16(a[mf], b, acc1[mf][nf], 0, 0, 0);
    }
  }

  // ---------------- add gathered Pab rows (packed-fragment layout) ----------------
  // j-side: ~4 unique rows per block -> L1/L2 hit + broadcast. i-side: random, L3-resident.
  #pragma unroll
  for (int mf = 0; mf < 4; mf++) {
    #pragma unroll
    for (int r = 0; r < 4; r++) {
      int row = mf * 16 + lhi * 4 + r;
      int gi = idxi[row], gj = idxj[row];
      bf16x8 pa = *(const bf16x8*)(pab + (size_t)gi * 1024 + llo * 32 + wid * 8);
      bf16x8 pb = *(const bf16x8*)(pab + (size_t)gj * 1024 + 512 + llo * 32 + wid * 8);
      #pragma unroll
      for (int nf = 0; nf < 8; nf++)
        acc1[mf][nf][r] += bf2f(pa[nf]) + bf2f(pb[nf]);
    }
  }
  __syncthreads();  // all GEMM_c LDS reads done before hid overwrites abuf

  // ---------------- bias + relu -> hid (XOR-swizzled, K=512) ----------------
  #pragma unroll
  for (int nf = 0; nf < 8; nf++) {
    int col = wid * 128 + nf * 16 + llo;
    float bb = b1[col];
    int cs = col >> 3, cl = col & 7;
    #pragma unroll
    for (int mf = 0; mf < 4; mf++) {
      #pragma unroll
      for (int r = 0; r < 4; r++) {
        int row = mf * 16 + lhi * 4 + r;
        float v = acc1[mf][nf][r] + bb;
        v = v > 0.f ? v : 0.f;
        hid[row * 512 + ((cs ^ (row & 7)) * 8) + cl] = f2bf(v);
      }
    }
  }
  __syncthreads();

  // ---------------- GEMM2: [64 x 512] @ [512 x 256] ----------------
  f32x4 acc2[4][4] = {};
  const bf16x8* bp2 = (const bf16x8*)w2p;
  const int bcol2 = wid * 64 + llo;
  #pragma unroll
  for (int kk = 0; kk < 512; kk += 32) {
    const int ks = kk >> 3;
    bf16x8 a[4];
    #pragma unroll
    for (int mf = 0; mf < 4; mf++) {
      int row = mf * 16 + llo;
      a[mf] = *(const bf16x8*)(hid + row * 512 + (((ks + lhi) ^ swz) * 8));
    }
    const bf16x8* bb = bp2 + (size_t)(ks + lhi) * 256 + bcol2;
    #pragma unroll
    for (int nf = 0; nf < 4; nf++) {
      bf16x8 b = bb[nf * 16];
      #pragma unroll
      for (int mf = 0; mf < 4; mf++)
        acc2[mf][nf] = __builtin_amdgcn_mfma_f32_16x16x32_bf16(a[mf], b, acc2[mf][nf], 0, 0, 0);
    }
  }

  // ---------------- LayerNorm in registers ----------------
  float bb2[4], gg[4], be[4];
  #pragma unroll
  for (int nf = 0; nf < 4; nf++) {
    int col = bcol2 + nf * 16;
    bb2[nf] = b2[col]; gg[nf] = gam[col]; be[nf] = bet[col];
  }
  #pragma unroll
  for (int mf = 0; mf < 4; mf++)
    #pragma unroll
    for (int nf = 0; nf < 4; nf++)
      #pragma unroll
      for (int r = 0; r < 4; r++)
        acc2[mf][nf][r] += bb2[nf];

  float S[4][4], Q[4][4];
  #pragma unroll
  for (int mf = 0; mf < 4; mf++) {
    #pragma unroll
    for (int r = 0; r < 4; r++) {
      float s = 0.f, q = 0.f;
      #pragma unroll
      for (int nf = 0; nf < 4; nf++) {
        float v = acc2[mf][nf][r];
        s += v; q += v * v;
      }
      S[mf][r] = s; Q[mf][r] = q;
    }
  }
  #pragma unroll
  for (int m = 1; m <= 8; m <<= 1) {
    #pragma unroll
    for (int mf = 0; mf < 4; mf++)
      #pragma unroll
      for (int r = 0; r < 4; r++) {
        S[mf][r] += __shfl_xor(S[mf][r], m);
        Q[mf][r] += __shfl_xor(Q[mf][r], m);
      }
  }
  if (llo == 0) {
    #pragma unroll
    for (int mf = 0; mf < 4; mf++)
      #pragma unroll
      for (int r = 0; r < 4; r++) {
        int row = mf * 16 + lhi * 4 + r;
        pS[wid * 64 + row] = S[mf][r];
        pQ[wid * 64 + row] = Q[mf][r];
      }
  }
  __syncthreads();

  float mu[4][4], rsv[4][4];
  #pragma unroll
  for (int mf = 0; mf < 4; mf++) {
    #pragma unroll
    for (int r = 0; r < 4; r++) {
      int row = mf * 16 + lhi * 4 + r;
      float s = pS[row] + pS[64 + row] + pS[128 + row] + pS[192 + row];
      float q = pQ[row] + pQ[64 + row] + pQ[128 + row] + pQ[192 + row];
      float m_ = s * (1.f / 256.f);
      mu[mf][r]  = m_;
      rsv[mf][r] = rsqrtf(q * (1.f / 256.f) - m_ * m_ + 1e-5f);
    }
  }

  #pragma unroll
  for (int mf = 0; mf < 4; mf++) {
    #pragma unroll
    for (int r = 0; r < 4; r++) {
      int erow = eidx[mf * 16 + lhi * 4 + r];
      const float* rp = ea  + (size_t)erow * DD + bcol2;
      float*       op = out + (size_t)erow * DD + bcol2;
      #pragma unroll
      for (int nf = 0; nf < 4; nf++) {
        float v = (acc2[mf][nf][r] - mu[mf][r]) * rsv[mf][r] * gg[nf] + be[nf] + rp[nf * 16];
        op[nf * 16] = v;
      }
    }
  }
}

// ---------------- node kernel (R3-proven structure) ----------------
__global__ __launch_bounds__(256, 2)
void fused_node(const float* __restrict__ x,
                const short* __restrict__ xb,
                const short* __restrict__ aggb,
                const short* __restrict__ w1p,
                const float* __restrict__ b1,
                const short* __restrict__ w2p,
                const float* __restrict__ b2,
                const float* __restrict__ gam,
                const float* __restrict__ bet,
                float* __restrict__ out)
{
  constexpr int HP = 520;
  __shared__ __align__(16) short hid[64 * HP];
  __shared__ float pS[4][64], pQ[4][64];

  const int tid  = threadIdx.x;
  const int lane = tid & 63;
  const int wid  = tid >> 6;
  const int m0   = blockIdx.x * 64;
  const int lhi  = lane >> 4;
  const int llo  = lane & 15;

  const short* pI[4]; const short* pJ[4];
  #pragma unroll
  for (int mf = 0; mf < 4; mf++) {
    int rr = min(m0 + mf * 16 + llo, NNODE - 1);
    pI[mf] = xb + (size_t)rr * DD;
    pJ[mf] = aggb + (size_t)rr * DD;
  }

  f32x4 acc1[4][8] = {};
  const bf16x8* bp1 = (const bf16x8*)w1p;
  const int bcol1 = wid * 128 + llo;

  #pragma unroll
  for (int s = 0; s < 8; s++) {
    #pragma unroll
    for (int kk = 0; kk < 64; kk += 32) {
      const int ko = s * 64 + kk + lhi * 8;
      bf16x8 a[4];
      #pragma unroll
      for (int mf = 0; mf < 4; mf++) {
        if (s < 4) a[mf] = *(const bf16x8*)(pI[mf] + ko);
        else       a[mf] = *(const bf16x8*)(pJ[mf] + (ko - 256));
      }
      const bf16x8* bb = bp1 + (size_t)(s * 8 + (kk >> 3) + lhi) * 512 + bcol1;
      #pragma unroll
      for (int nf = 0; nf < 8; nf++) {
        bf16x8 b = bb[nf * 16];
        #pragma unroll
        for (int mf = 0; mf < 4; mf++)
          acc1[mf][nf] = __builtin_amdgcn_mfma_f32_16x16x32_bf16(a[mf], b, acc1[mf][nf], 0, 0, 0);
      }
    }
  }

  #pragma unroll
  for (int nf = 0; nf < 8; nf++) {
    int col = wid * 128 + nf * 16 + llo;
    float bb = b1[col];
    #pragma unroll
    for (int mf = 0; mf < 4; mf++) {
      #pragma unroll
      for (int r = 0; r < 4; r++) {
        float v = acc1[mf][nf][r] + bb;
        v = v > 0.f ? v : 0.f;
        hid[(mf * 16 + lhi * 4 + r) * HP + col] = f2bf(v);
      }
    }
  }
  __syncthreads();

  f32x4 acc2[4][4] = {};
  const bf16x8* bp2 = (const bf16x8*)w2p;
  const int bcol2 = wid * 64 + llo;
  #pragma unroll
  for (int kk = 0; kk < 512; kk += 32) {
    bf16x8 a[4];
    #pragma unroll
    for (int mf = 0; mf < 4; mf++)
      a[mf] = *(const bf16x8*)(hid + (mf * 16 + llo) * HP + kk + lhi * 8);
    const bf16x8* bb = bp2 + (size_t)((kk >> 3) + lhi) * 256 + bcol2;
    #pragma unroll
    for (int nf = 0; nf < 4; nf++) {
      bf16x8 b = bb[nf * 16];
      #pragma unroll
      for (int mf = 0; mf < 4; mf++)
        acc2[mf][nf] = __builtin_amdgcn_mfma_f32_16x16x32_bf16(a[mf], b, acc2[mf][nf], 0, 0, 0);
    }
  }

  float bb2[4], gg[4], be[4];
  #pragma unroll
  for (int nf = 0; nf < 4; nf++) {
    int col = bcol2 + nf * 16;
    bb2[nf] = b2[col]; gg[nf] = gam[col]; be[nf] = bet[col];
  }
  #pragma unroll
  for (int mf = 0; mf < 4; mf++)
    #pragma unroll
    for (int nf = 0; nf < 4; nf++)
      #pragma unroll
      for (int r = 0; r < 4; r++)
        acc2[mf][nf][r] += bb2[nf];

  float S[4][4], Q[4][4];
  #pragma unroll
  for (int mf = 0; mf < 4; mf++) {
    #pragma unroll
    for (int r = 0; r < 4; r++) {
      float s = 0.f, q = 0.f;
      #pragma unroll
      for (int nf = 0; nf < 4; nf++) {
        float v = acc2[mf][nf][r];
        s += v; q += v * v;
      }
      S[mf][r] = s; Q[mf][r] = q;
    }
  }
  #pragma unroll
  for (int m = 1; m <= 8; m <<= 1) {
    #pragma unroll
    for (int mf = 0; mf < 4; mf++)
      #pragma unroll
      for (int r = 0; r < 4; r++) {
        S[mf][r] += __shfl_xor(S[mf][r], m);
        Q[mf][r] += __shfl_xor(Q[mf][r], m);
      }
  }
  if (llo == 0) {
    #pragma unroll
    for (int mf = 0; mf < 4; mf++)
      #pragma unroll
      for (int r = 0; r < 4; r++) {
        int row = mf * 16 + lhi * 4 + r;
        pS[wid][row] = S[mf][r];
        pQ[wid][row] = Q[mf][r];
      }
  }
  __syncthreads();

  float mu[4][4], rsv[4][4];
  #pragma unroll
  for (int mf = 0; mf < 4; mf++) {
    #pragma unroll
    for (int r = 0; r < 4; r++) {
      int row = mf * 16 + lhi * 4 + r;
      float s = pS[0][row] + pS[1][row] + pS[2][row] + pS[3][row];
      float q = pQ[0][row] + pQ[1][row] + pQ[2][row] + pQ[3][row];
      float m_ = s * (1.f / 256.f);
      mu[mf][r]  = m_;
      rsv[mf][r] = rsqrtf(q * (1.f / 256.f) - m_ * m_ + 1e-5f);
    }
  }

  #pragma unroll
  for (int mf = 0; mf < 4; mf++) {
    #pragma unroll
    for (int r = 0; r < 4; r++) {
      int grow = m0 + mf * 16 + lhi * 4 + r;
      if (grow >= NNODE) continue;
      const float* rp = x   + (size_t)grow * DD + bcol2;
      float*       op = out + (size_t)grow * DD + bcol2;
      #pragma unroll
      for (int nf = 0; nf < 4; nf++) {
        float v = (acc2[mf][nf][r] - mu[mf][r]) * rsv[mf][r] * gg[nf] + be[nf] + rp[nf * 16];
        op[nf * 16] = v;
      }
    }
  }
}

extern "C" void kernel_launch(void* const* d_in, const int* in_sizes, int n_in,
                              void* d_out, int out_size, void* d_ws, size_t ws_size,
                              hipStream_t stream) {
  const float* x      = (const float*)d_in[0];
  const int*   ei     = (const int*)  d_in[1];
  const float* ea     = (const float*)d_in[2];
  const float* e_w1   = (const float*)d_in[3];
  const float* e_b1   = (const float*)d_in[4];
  const float* e_w2   = (const float*)d_in[5];
  const float* e_b2   = (const float*)d_in[6];
  const float* e_g    = (const float*)d_in[7];
  const float* e_beta = (const float*)d_in[8];
  const float* n_w1   = (const float*)d_in[9];
  const float* n_b1   = (const float*)d_in[10];
  const float* n_w2   = (const float*)d_in[11];
  const float* n_b2   = (const float*)d_in[12];
  const float* n_g    = (const float*)d_in[13];
  const float* n_beta = (const float*)d_in[14];

  float* out_x = (float*)d_out;
  float* out_e = (float*)d_out + (size_t)NNODE * DD;

  char* w = (char*)d_ws;
  short* xb    = (short*)(w);                   //  5,120,000 B
  short* aggb  = (short*)(w + 5120000);         //  5,120,000 B
  short* pab   = (short*)(w + 10240000);        // 20,480,000 B
  short* w1abp = (short*)(w + 30720000);        //    524,288 B
  short* w1cp  = (short*)(w + 31244288);        //    262,144 B
  short* ew2p  = (short*)(w + 31506432);        //    262,144 B
  short* nw1p  = (short*)(w + 31768576);        //    524,288 B
  short* nw2p  = (short*)(w + 32292864);        //    262,144 B
  int*   deg   = (int*)  (w + 32555008);        //     40,960 B
  int*   cur   = (int*)  (w + 32595968);        //     40,960 B
  int*   rs    = (int*)  (w + 32636928);        //     40,976 B
  int*   csr   = (int*)  (w + 32677904);        //    640,000 B  -> ~33.3 MB total

  hipMemsetAsync(deg, 0, 81920, stream);  // deg + cursor

  cast_x_kernel<<<(NNODE * DD + 255) / 256, 256, 0, stream>>>(x, xb, NNODE * DD);
  pack_ew1_kernel<<<(768 * 512 + 255) / 256, 256, 0, stream>>>(e_w1, w1abp, w1cp);
  pack_w_kernel<<<(512 * 512 + 255) / 256, 256, 0, stream>>>(n_w1, nw1p, 512, 512);
  pack_w_kernel<<<(512 * 256 + 255) / 256, 256, 0, stream>>>(e_w2, ew2p, 512, 256);
  pack_w_kernel<<<(512 * 256 + 255) / 256, 256, 0, stream>>>(n_w2, nw2p, 512, 256);

  hist_kernel<<<(NEDGE + 255) / 256, 256, 0, stream>>>(ei, deg);
  scan_kernel<<<1, 256, 0, stream>>>(deg, rs);
  scatter_kernel<<<(NEDGE + 255) / 256, 256, 0, stream>>>(ei, rs, cur, csr);

  precomp_pab<<<dim3((NNODE + 63) / 64, 2), 256, 0, stream>>>(xb, w1abp, pab);

  fused_edge<<<NEDGE / 64, 256, 0, stream>>>(ei, csr, ea, pab, w1cp, e_b1,
                                             ew2p, e_b2, e_g, e_beta, out_e);
  agg_kernel<<<(NNODE + 3) / 4, 256, 0, stream>>>(out_e, rs, csr, aggb);
  fused_node<<<(NNODE + 63) / 64, 256, 0, stream>>>(x, xb, aggb, nw1p, n_b1,
                                                    nw2p, n_b2, n_g, n_beta, out_x);
}

// Round 9
// 474.168 us; speedup vs baseline: 1.4810x; 1.1156x over previous
//
#include <hip/hip_runtime.h>

#define NNODE 10000
#define NEDGE 160000
#define DD 256

using f32x4  = __attribute__((ext_vector_type(4))) float;
using bf16x8 = __attribute__((ext_vector_type(8))) short;
using u32x4  = __attribute__((ext_vector_type(4))) unsigned;

__device__ inline short f2bf(float f) {
  unsigned u = __float_as_uint(f);
  unsigned r = (u + 0x7fffu + ((u >> 16) & 1u)) >> 16;
  return (short)(unsigned short)r;
}

__device__ inline float bf2f(short s) {
  return __uint_as_float(((unsigned)(unsigned short)s) << 16);
}

__device__ inline unsigned pkbf(float a, float b) {
  unsigned r;
  asm("v_cvt_pk_bf16_f32 %0, %1, %2" : "=v"(r) : "v"(a), "v"(b));
  return r;
}

__global__ void cast_x_kernel(const float* __restrict__ x, short* __restrict__ xb, int total) {
  int i = blockIdx.x * 256 + threadIdx.x;
  if (i < total) xb[i] = f2bf(x[i]);
}

// generic pack w[K][N] (f32) -> p[(k>>3)][n][k&7] (bf16)
__global__ void pack_w_kernel(const float* __restrict__ w, short* __restrict__ p, int K, int N) {
  int idx = blockIdx.x * 256 + threadIdx.x;
  if (idx >= K * N) return;
  int k = idx / N, n = idx - k * N;
  p[(size_t)(k >> 3) * N * 8 + (size_t)n * 8 + (k & 7)] = f2bf(w[idx]);
}

// e_w1 [768][512] split: rows 0..255 -> w1abp half0, 256..511 -> w1abp half1 (N=1024),
// rows 512..767 -> w1cp (N=512). Same MFMA-native (k>>3, n, k&7) layout.
__global__ void pack_ew1_kernel(const float* __restrict__ w, short* __restrict__ w1abp,
                                short* __restrict__ w1cp) {
  int idx = blockIdx.x * 256 + threadIdx.x;
  if (idx >= 768 * 512) return;
  int k = idx >> 9, n = idx & 511;
  short v = f2bf(w[idx]);
  if (k < 256) {
    w1abp[(size_t)(k >> 3) * 1024 * 8 + (size_t)n * 8 + (k & 7)] = v;
  } else if (k < 512) {
    int kk = k - 256;
    w1abp[(size_t)(kk >> 3) * 1024 * 8 + (size_t)(512 + n) * 8 + (kk & 7)] = v;
  } else {
    int kk = k - 512;
    w1cp[(size_t)(kk >> 3) * 512 * 8 + (size_t)n * 8 + (kk & 7)] = v;
  }
}

// ---------------- CSR build ----------------
__global__ void hist_kernel(const int* __restrict__ ei, int* __restrict__ deg) {
  int e = blockIdx.x * 256 + threadIdx.x;
  if (e < NEDGE) {
    int j = ei[NEDGE + e]; j = min(max(j, 0), NNODE - 1);
    atomicAdd(&deg[j], 1);
  }
}

__global__ void scan_kernel(const int* __restrict__ deg, int* __restrict__ row_start) {
  __shared__ int part[256];
  int t = threadIdx.x;
  const int CH = 40;
  int base = t * CH;
  int s = 0;
  for (int i = 0; i < CH; i++) {
    int idx = base + i;
    s += (idx < NNODE) ? deg[idx] : 0;
  }
  part[t] = s;
  __syncthreads();
  for (int off = 1; off < 256; off <<= 1) {
    int v = (t >= off) ? part[t - off] : 0;
    __syncthreads();
    part[t] += v;
    __syncthreads();
  }
  int run = (t == 0) ? 0 : part[t - 1];
  for (int i = 0; i < CH; i++) {
    int idx = base + i;
    if (idx < NNODE) { row_start[idx] = run; run += deg[idx]; }
  }
  if (t == 255) row_start[NNODE] = part[255];
}

__global__ void scatter_kernel(const int* __restrict__ ei, const int* __restrict__ row_start,
                               int* __restrict__ cursor, int* __restrict__ csr) {
  int e = blockIdx.x * 256 + threadIdx.x;
  if (e < NEDGE) {
    int j = ei[NEDGE + e]; j = min(max(j, 0), NNODE - 1);
    int p = atomicAdd(&cursor[j], 1);
    csr[row_start[j] + p] = e;
  }
}

// ---------------- precomp: Pab = x @ [W1a | W1b], packed-fragment bf16 ----------------
__global__ __launch_bounds__(256, 2)
void precomp_pab(const short* __restrict__ xb, const short* __restrict__ w1abp,
                 short* __restrict__ pab) {
  __shared__ __align__(16) short abuf[2048 * 8];  // 32 KB swizzled

  const int tid  = threadIdx.x;
  const int lane = tid & 63;
  const int wid  = tid >> 6;
  const int lhi  = lane >> 4;
  const int llo  = lane & 15;
  const int swz  = llo & 7;
  const int m0   = blockIdx.x * 64;
  const int h    = blockIdx.y;

  #pragma unroll
  for (int q = 0; q < 8; q++) {
    int S = wid * 512 + q * 64 + lane;
    int row = S >> 5;
    int segp = S & 31;
    int seg = segp ^ (row & 7);
    int rowg = min(m0 + row, NNODE - 1);
    __builtin_amdgcn_global_load_lds(
        (const int*)((const char*)xb + (size_t)rowg * 512 + seg * 16),
        (int*)(abuf + (size_t)(wid * 512 + q * 64) * 8), 16, 0, 0);
  }
  __syncthreads();

  f32x4 acc1[4][8] = {};
  const bf16x8* bp1 = (const bf16x8*)w1abp;
  #pragma unroll
  for (int kk = 0; kk < 256; kk += 32) {
    const int ks = kk >> 3;
    bf16x8 a[4];
    #pragma unroll
    for (int mf = 0; mf < 4; mf++)
      a[mf] = *(const bf16x8*)(abuf + ((mf * 16 + llo) * 32 + ((ks + lhi) ^ swz)) * 8);
    const bf16x8* bb = bp1 + (size_t)(ks + lhi) * 1024 + h * 512 + wid * 128 + llo;
    #pragma unroll
    for (int nf = 0; nf < 8; nf++) {
      bf16x8 b = bb[nf * 16];
      #pragma unroll
      for (int mf = 0; mf < 4; mf++)
        acc1[mf][nf] = __builtin_amdgcn_mfma_f32_16x16x32_bf16(a[mf], b, acc1[mf][nf], 0, 0, 0);
    }
  }

  #pragma unroll
  for (int mf = 0; mf < 4; mf++) {
    #pragma unroll
    for (int r = 0; r < 4; r++) {
      int row = m0 + mf * 16 + lhi * 4 + r;
      if (row < NNODE) {
        u32x4 wv = { pkbf(acc1[mf][0][r], acc1[mf][1][r]),
                     pkbf(acc1[mf][2][r], acc1[mf][3][r]),
                     pkbf(acc1[mf][4][r], acc1[mf][5][r]),
                     pkbf(acc1[mf][6][r], acc1[mf][7][r]) };
        *(u32x4*)(pab + (size_t)row * 1024 + h * 512 + llo * 32 + wid * 8) = wv;
      }
    }
  }
}

// ---------------- edge kernel (CSR-ordered, fused aggregation) ----------------
// Block b: edges csr[64b..64b+63] (grouped by j). hidden = relu(ea@W1c + Pab[i]
// + Pab[j] + b1); new_edge = ea + LN(hidden@W2 + b2). new_edge rows assembled in
// LDS, stored as full contiguous 1KB rows (nt), and segment-summed by j into
// f32 agg via ~few coalesced atomic row-flushes per block.
__global__ __launch_bounds__(256, 2)
void fused_edge(const int* __restrict__ ei,
                const int* __restrict__ csr,
                const float* __restrict__ ea,
                const short* __restrict__ pab,
                const short* __restrict__ w1cp,
                const float* __restrict__ b1,
                const short* __restrict__ w2p,
                const float* __restrict__ b2,
                const float* __restrict__ gam,
                const float* __restrict__ bet,
                float* __restrict__ out,
                float* __restrict__ aggf)
{
  // union region: abuf (32KB stage) -> hid (64KB bf16) -> outt (66.56KB f32)
  __shared__ __align__(16) char smem[66560];
  __shared__ int eidx[64], idxi[64], idxj[64];
  __shared__ float pS[256], pQ[256];

  short* abuf = (short*)smem;   // [64 rows][32 segs of 8] bf16, swizzled
  short* hid  = (short*)smem;   // [64][512] bf16, XOR-swizzled
  float* outt = (float*)smem;   // [64][260] f32

  const int tid  = threadIdx.x;
  const int lane = tid & 63;
  const int wid  = tid >> 6;
  const int lhi  = lane >> 4;
  const int llo  = lane & 15;
  const int swz  = llo & 7;
  const int m0   = blockIdx.x * 64;

  if (tid < 64) {
    int e = csr[m0 + tid];
    eidx[tid] = e;
    int a = ei[e];
    int b = ei[NEDGE + e];
    idxi[tid] = min(max(a, 0), NNODE - 1);
    idxj[tid] = min(max(b, 0), NNODE - 1);
  }
  __syncthreads();

  // stage ea tile (64 gathered rows, f32 -> bf16, swizzled); rows 1KB-contiguous
  #pragma unroll
  for (int q = 0; q < 8; q++) {
    int S = q * 256 + tid;
    int row = S >> 5;
    int segp = S & 31;
    int seg = segp ^ (row & 7);
    const float* src = ea + (size_t)eidx[row] * 256 + seg * 8;
    f32x4 u0 = *(const f32x4*)src;
    f32x4 u1 = *(const f32x4*)(src + 4);
    u32x4 qv = { pkbf(u0.x, u0.y), pkbf(u0.z, u0.w), pkbf(u1.x, u1.y), pkbf(u1.z, u1.w) };
    *(u32x4*)(abuf + (size_t)S * 8) = qv;
  }
  __syncthreads();

  // ---------------- GEMM_c: [64 x 256] @ [256 x 512] ----------------
  f32x4 acc1[4][8] = {};
  const bf16x8* bp1 = (const bf16x8*)w1cp;
  #pragma unroll
  for (int kk = 0; kk < 256; kk += 32) {
    const int ks = kk >> 3;
    bf16x8 a[4];
    #pragma unroll
    for (int mf = 0; mf < 4; mf++)
      a[mf] = *(const bf16x8*)(abuf + ((mf * 16 + llo) * 32 + ((ks + lhi) ^ swz)) * 8);
    const bf16x8* bb = bp1 + (size_t)(ks + lhi) * 512 + wid * 128 + llo;
    #pragma unroll
    for (int nf = 0; nf < 8; nf++) {
      bf16x8 b = bb[nf * 16];
      #pragma unroll
      for (int mf = 0; mf < 4; mf++)
        acc1[mf][nf] = __builtin_amdgcn_mfma_f32_16x16x32_bf16(a[mf], b, acc1[mf][nf], 0, 0, 0);
    }
  }

  // add gathered Pab rows (packed-fragment layout); j-side L2-local via CSR order
  #pragma unroll
  for (int mf = 0; mf < 4; mf++) {
    #pragma unroll
    for (int r = 0; r < 4; r++) {
      int row = mf * 16 + lhi * 4 + r;
      int gi = idxi[row], gj = idxj[row];
      bf16x8 pa = *(const bf16x8*)(pab + (size_t)gi * 1024 + llo * 32 + wid * 8);
      bf16x8 pb = *(const bf16x8*)(pab + (size_t)gj * 1024 + 512 + llo * 32 + wid * 8);
      #pragma unroll
      for (int nf = 0; nf < 8; nf++)
        acc1[mf][nf][r] += bf2f(pa[nf]) + bf2f(pb[nf]);
    }
  }
  __syncthreads();  // GEMM_c LDS reads done before hid overwrites abuf

  // ---------------- bias + relu -> hid (XOR-swizzled, K=512) ----------------
  #pragma unroll
  for (int nf = 0; nf < 8; nf++) {
    int col = wid * 128 + nf * 16 + llo;
    float bb = b1[col];
    int cs = col >> 3, cl = col & 7;
    #pragma unroll
    for (int mf = 0; mf < 4; mf++) {
      #pragma unroll
      for (int r = 0; r < 4; r++) {
        int row = mf * 16 + lhi * 4 + r;
        float v = acc1[mf][nf][r] + bb;
        v = v > 0.f ? v : 0.f;
        hid[row * 512 + ((cs ^ (row & 7)) * 8) + cl] = f2bf(v);
      }
    }
  }
  __syncthreads();

  // ---------------- GEMM2: [64 x 512] @ [512 x 256] ----------------
  f32x4 acc2[4][4] = {};
  const bf16x8* bp2 = (const bf16x8*)w2p;
  const int bcol2 = wid * 64 + llo;
  #pragma unroll
  for (int kk = 0; kk < 512; kk += 32) {
    const int ks = kk >> 3;
    bf16x8 a[4];
    #pragma unroll
    for (int mf = 0; mf < 4; mf++) {
      int row = mf * 16 + llo;
      a[mf] = *(const bf16x8*)(hid + row * 512 + (((ks + lhi) ^ swz) * 8));
    }
    const bf16x8* bb = bp2 + (size_t)(ks + lhi) * 256 + bcol2;
    #pragma unroll
    for (int nf = 0; nf < 4; nf++) {
      bf16x8 b = bb[nf * 16];
      #pragma unroll
      for (int mf = 0; mf < 4; mf++)
        acc2[mf][nf] = __builtin_amdgcn_mfma_f32_16x16x32_bf16(a[mf], b, acc2[mf][nf], 0, 0, 0);
    }
  }

  // ---------------- LayerNorm stats ----------------
  float bb2[4], gg[4], be[4];
  #pragma unroll
  for (int nf = 0; nf < 4; nf++) {
    int col = bcol2 + nf * 16;
    bb2[nf] = b2[col]; gg[nf] = gam[col]; be[nf] = bet[col];
  }
  #pragma unroll
  for (int mf = 0; mf < 4; mf++)
    #pragma unroll
    for (int nf = 0; nf < 4; nf++)
      #pragma unroll
      for (int r = 0; r < 4; r++)
        acc2[mf][nf][r] += bb2[nf];

  float S[4][4], Q[4][4];
  #pragma unroll
  for (int mf = 0; mf < 4; mf++) {
    #pragma unroll
    for (int r = 0; r < 4; r++) {
      float s = 0.f, q = 0.f;
      #pragma unroll
      for (int nf = 0; nf < 4; nf++) {
        float v = acc2[mf][nf][r];
        s += v; q += v * v;
      }
      S[mf][r] = s; Q[mf][r] = q;
    }
  }
  #pragma unroll
  for (int m = 1; m <= 8; m <<= 1) {
    #pragma unroll
    for (int mf = 0; mf < 4; mf++)
      #pragma unroll
      for (int r = 0; r < 4; r++) {
        S[mf][r] += __shfl_xor(S[mf][r], m);
        Q[mf][r] += __shfl_xor(Q[mf][r], m);
      }
  }
  if (llo == 0) {
    #pragma unroll
    for (int mf = 0; mf < 4; mf++)
      #pragma unroll
      for (int r = 0; r < 4; r++) {
        int row = mf * 16 + lhi * 4 + r;
        pS[wid * 64 + row] = S[mf][r];
        pQ[wid * 64 + row] = Q[mf][r];
      }
  }
  __syncthreads();  // also guarantees all GEMM2 hid reads complete

  float mu[4][4], rsv[4][4];
  #pragma unroll
  for (int mf = 0; mf < 4; mf++) {
    #pragma unroll
    for (int r = 0; r < 4; r++) {
      int row = mf * 16 + lhi * 4 + r;
      float s = pS[row] + pS[64 + row] + pS[128 + row] + pS[192 + row];
      float q = pQ[row] + pQ[64 + row] + pQ[128 + row] + pQ[192 + row];
      float m_ = s * (1.f / 256.f);
      mu[mf][r]  = m_;
      rsv[mf][r] = rsqrtf(q * (1.f / 256.f) - m_ * m_ + 1e-5f);
    }
  }

  // write LN result (no residual yet) into outt[64][260] f32 (overwrites hid)
  #pragma unroll
  for (int mf = 0; mf < 4; mf++) {
    #pragma unroll
    for (int r = 0; r < 4; r++) {
      int row = mf * 16 + lhi * 4 + r;
      #pragma unroll
      for (int nf = 0; nf < 4; nf++) {
        float v = (acc2[mf][nf][r] - mu[mf][r]) * rsv[mf][r] * gg[nf] + be[nf];
        outt[row * 260 + bcol2 + nf * 16] = v;
      }
    }
  }
  __syncthreads();

  // ---------------- store loop: full 1KB contiguous rows + residual ----------------
  #pragma unroll
  for (int it = 0; it < 16; it++) {
    int row = it * 4 + wid;
    int e = eidx[row];
    f32x4 resid = *((const f32x4*)(ea + (size_t)e * 256) + lane);
    f32x4 o4 = *((const f32x4*)(outt + row * 260) + lane);
    o4 += resid;
    __builtin_nontemporal_store(o4, (f32x4*)(out + (size_t)e * 256) + lane);
    *((f32x4*)(outt + row * 260) + lane) = o4;  // full new_edge row for the reduce
  }
  __syncthreads();

  // ---------------- fused segment-sum over j (sorted within block) ----------------
  {
    int c = tid;  // column 0..255
    float acc = 0.f;
    int cj = idxj[0];
    #pragma unroll 8
    for (int r = 0; r < 64; r++) {
      int jr = idxj[r];
      if (jr != cj) {  // uniform branch
        atomicAdd(&aggf[(size_t)cj * 256 + c], acc);
        acc = 0.f; cj = jr;
      }
      acc += outt[r * 260 + c];
    }
    atomicAdd(&aggf[(size_t)cj * 256 + c], acc);
  }
}

// ---------------- node kernel (R3-proven structure; f32 agg input) ----------------
__global__ __launch_bounds__(256, 2)
void fused_node(const float* __restrict__ x,
                const short* __restrict__ xb,
                const float* __restrict__ aggf,
                const short* __restrict__ w1p,
                const float* __restrict__ b1,
                const short* __restrict__ w2p,
                const float* __restrict__ b2,
                const float* __restrict__ gam,
                const float* __restrict__ bet,
                float* __restrict__ out)
{
  constexpr int HP = 520;
  __shared__ __align__(16) short hid[64 * HP];
  __shared__ float pS[4][64], pQ[4][64];

  const int tid  = threadIdx.x;
  const int lane = tid & 63;
  const int wid  = tid >> 6;
  const int m0   = blockIdx.x * 64;
  const int lhi  = lane >> 4;
  const int llo  = lane & 15;

  const short* pI[4]; const float* pJ[4];
  #pragma unroll
  for (int mf = 0; mf < 4; mf++) {
    int rr = min(m0 + mf * 16 + llo, NNODE - 1);
    pI[mf] = xb + (size_t)rr * DD;
    pJ[mf] = aggf + (size_t)rr * DD;
  }

  f32x4 acc1[4][8] = {};
  const bf16x8* bp1 = (const bf16x8*)w1p;
  const int bcol1 = wid * 128 + llo;

  #pragma unroll
  for (int s = 0; s < 8; s++) {
    #pragma unroll
    for (int kk = 0; kk < 64; kk += 32) {
      const int ko = s * 64 + kk + lhi * 8;
      bf16x8 a[4];
      #pragma unroll
      for (int mf = 0; mf < 4; mf++) {
        if (s < 4) {
          a[mf] = *(const bf16x8*)(pI[mf] + ko);
        } else {
          const float* fp = pJ[mf] + (ko - 256);
          f32x4 u0 = *(const f32x4*)fp;
          f32x4 u1 = *(const f32x4*)(fp + 4);
          u32x4 q = { pkbf(u0.x, u0.y), pkbf(u0.z, u0.w),
                      pkbf(u1.x, u1.y), pkbf(u1.z, u1.w) };
          a[mf] = __builtin_bit_cast(bf16x8, q);
        }
      }
      const bf16x8* bb = bp1 + (size_t)(s * 8 + (kk >> 3) + lhi) * 512 + bcol1;
      #pragma unroll
      for (int nf = 0; nf < 8; nf++) {
        bf16x8 b = bb[nf * 16];
        #pragma unroll
        for (int mf = 0; mf < 4; mf++)
          acc1[mf][nf] = __builtin_amdgcn_mfma_f32_16x16x32_bf16(a[mf], b, acc1[mf][nf], 0, 0, 0);
      }
    }
  }

  #pragma unroll
  for (int nf = 0; nf < 8; nf++) {
    int col = wid * 128 + nf * 16 + llo;
    float bb = b1[col];
    #pragma unroll
    for (int mf = 0; mf < 4; mf++) {
      #pragma unroll
      for (int r = 0; r < 4; r++) {
        float v = acc1[mf][nf][r] + bb;
        v = v > 0.f ? v : 0.f;
        hid[(mf * 16 + lhi * 4 + r) * HP + col] = f2bf(v);
      }
    }
  }
  __syncthreads();

  f32x4 acc2[4][4] = {};
  const bf16x8* bp2 = (const bf16x8*)w2p;
  const int bcol2 = wid * 64 + llo;
  #pragma unroll
  for (int kk = 0; kk < 512; kk += 32) {
    bf16x8 a[4];
    #pragma unroll
    for (int mf = 0; mf < 4; mf++)
      a[mf] = *(const bf16x8*)(hid + (mf * 16 + llo) * HP + kk + lhi * 8);
    const bf16x8* bb = bp2 + (size_t)((kk >> 3) + lhi) * 256 + bcol2;
    #pragma unroll
    for (int nf = 0; nf < 4; nf++) {
      bf16x8 b = bb[nf * 16];
      #pragma unroll
      for (int mf = 0; mf < 4; mf++)
        acc2[mf][nf] = __builtin_amdgcn_mfma_f32_16x16x32_bf16(a[mf], b, acc2[mf][nf], 0, 0, 0);
    }
  }

  float bb2[4], gg[4], be[4];
  #pragma unroll
  for (int nf = 0; nf < 4; nf++) {
    int col = bcol2 + nf * 16;
    bb2[nf] = b2[col]; gg[nf] = gam[col]; be[nf] = bet[col];
  }
  #pragma unroll
  for (int mf = 0; mf < 4; mf++)
    #pragma unroll
    for (int nf = 0; nf < 4; nf++)
      #pragma unroll
      for (int r = 0; r < 4; r++)
        acc2[mf][nf][r] += bb2[nf];

  float S[4][4], Q[4][4];
  #pragma unroll
  for (int mf = 0; mf < 4; mf++) {
    #pragma unroll
    for (int r = 0; r < 4; r++) {
      float s = 0.f, q = 0.f;
      #pragma unroll
      for (int nf = 0; nf < 4; nf++) {
        float v = acc2[mf][nf][r];
        s += v; q += v * v;
      }
      S[mf][r] = s; Q[mf][r] = q;
    }
  }
  #pragma unroll
  for (int m = 1; m <= 8; m <<= 1) {
    #pragma unroll
    for (int mf = 0; mf < 4; mf++)
      #pragma unroll
      for (int r = 0; r < 4; r++) {
        S[mf][r] += __shfl_xor(S[mf][r], m);
        Q[mf][r] += __shfl_xor(Q[mf][r], m);
      }
  }
  if (llo == 0) {
    #pragma unroll
    for (int mf = 0; mf < 4; mf++)
      #pragma unroll
      for (int r = 0; r < 4; r++) {
        int row = mf * 16 + lhi * 4 + r;
        pS[wid][row] = S[mf][r];
        pQ[wid][row] = Q[mf][r];
      }
  }
  __syncthreads();

  float mu[4][4], rsv[4][4];
  #pragma unroll
  for (int mf = 0; mf < 4; mf++) {
    #pragma unroll
    for (int r = 0; r < 4; r++) {
      int row = mf * 16 + lhi * 4 + r;
      float s = pS[0][row] + pS[1][row] + pS[2][row] + pS[3][row];
      float q = pQ[0][row] + pQ[1][row] + pQ[2][row] + pQ[3][row];
      float m_ = s * (1.f / 256.f);
      mu[mf][r]  = m_;
      rsv[mf][r] = rsqrtf(q * (1.f / 256.f) - m_ * m_ + 1e-5f);
    }
  }

  #pragma unroll
  for (int mf = 0; mf < 4; mf++) {
    #pragma unroll
    for (int r = 0; r < 4; r++) {
      int grow = m0 + mf * 16 + lhi * 4 + r;
      if (grow >= NNODE) continue;
      const float* rp = x   + (size_t)grow * DD + bcol2;
      float*       op = out + (size_t)grow * DD + bcol2;
      #pragma unroll
      for (int nf = 0; nf < 4; nf++) {
        float v = (acc2[mf][nf][r] - mu[mf][r]) * rsv[mf][r] * gg[nf] + be[nf] + rp[nf * 16];
        op[nf * 16] = v;
      }
    }
  }
}

extern "C" void kernel_launch(void* const* d_in, const int* in_sizes, int n_in,
                              void* d_out, int out_size, void* d_ws, size_t ws_size,
                              hipStream_t stream) {
  const float* x      = (const float*)d_in[0];
  const int*   ei     = (const int*)  d_in[1];
  const float* ea     = (const float*)d_in[2];
  const float* e_w1   = (const float*)d_in[3];
  const float* e_b1   = (const float*)d_in[4];
  const float* e_w2   = (const float*)d_in[5];
  const float* e_b2   = (const float*)d_in[6];
  const float* e_g    = (const float*)d_in[7];
  const float* e_beta = (const float*)d_in[8];
  const float* n_w1   = (const float*)d_in[9];
  const float* n_b1   = (const float*)d_in[10];
  const float* n_w2   = (const float*)d_in[11];
  const float* n_b2   = (const float*)d_in[12];
  const float* n_g    = (const float*)d_in[13];
  const float* n_beta = (const float*)d_in[14];

  float* out_x = (float*)d_out;
  float* out_e = (float*)d_out + (size_t)NNODE * DD;

  char* w = (char*)d_ws;
  short* xb    = (short*)(w);                   //  5,120,000 B
  short* pab   = (short*)(w + 5120000);         // 20,480,000 B
  short* w1abp = (short*)(w + 25600000);        //    524,288 B
  short* w1cp  = (short*)(w + 26124288);        //    262,144 B
  short* ew2p  = (short*)(w + 26386432);        //    262,144 B
  short* nw1p  = (short*)(w + 26648576);        //    524,288 B
  short* nw2p  = (short*)(w + 27172864);        //    262,144 B
  float* aggf  = (float*)(w + 27435008);        // 10,240,000 B
  int*   deg   = (int*)  (w + 37675008);        //     40,960 B
  int*   cur   = (int*)  (w + 37715968);        //     40,960 B
  int*   rs    = (int*)  (w + 37756928);        //     40,976 B
  int*   csr   = (int*)  (w + 37797904);        //    640,000 B -> ~38.4 MB total

  hipMemsetAsync(deg, 0, 81920, stream);                          // deg + cursor
  hipMemsetAsync(aggf, 0, (size_t)NNODE * DD * sizeof(float), stream);

  cast_x_kernel<<<(NNODE * DD + 255) / 256, 256, 0, stream>>>(x, xb, NNODE * DD);
  pack_ew1_kernel<<<(768 * 512 + 255) / 256, 256, 0, stream>>>(e_w1, w1abp, w1cp);
  pack_w_kernel<<<(512 * 512 + 255) / 256, 256, 0, stream>>>(n_w1, nw1p, 512, 512);
  pack_w_kernel<<<(512 * 256 + 255) / 256, 256, 0, stream>>>(e_w2, ew2p, 512, 256);
  pack_w_kernel<<<(512 * 256 + 255) / 256, 256, 0, stream>>>(n_w2, nw2p, 512, 256);

  hist_kernel<<<(NEDGE + 255) / 256, 256, 0, stream>>>(ei, deg);
  scan_kernel<<<1, 256, 0, stream>>>(deg, rs);
  scatter_kernel<<<(NEDGE + 255) / 256, 256, 0, stream>>>(ei, rs, cur, csr);

  precomp_pab<<<dim3((NNODE + 63) / 64, 2), 256, 0, stream>>>(xb, w1abp, pab);

  fused_edge<<<NEDGE / 64, 256, 0, stream>>>(ei, csr, ea, pab, w1cp, e_b1,
                                             ew2p, e_b2, e_g, e_beta, out_e, aggf);
  fused_node<<<(NNODE + 63) / 64, 256, 0, stream>>>(x, xb, aggf, nw1p, n_b1,
                                                    nw2p, n_b2, n_g, n_beta, out_x);
}

// Round 10
// 452.085 us; speedup vs baseline: 1.5534x; 1.0488x over previous
//
#include <hip/hip_runtime.h>

#define NNODE 10000
#define NEDGE 160000
#define DD 256

using f32x4  = __attribute__((ext_vector_type(4))) float;
using bf16x8 = __attribute__((ext_vector_type(8))) short;
using u32x4  = __attribute__((ext_vector_type(4))) unsigned;

__device__ inline short f2bf(float f) {
  unsigned u = __float_as_uint(f);
  unsigned r = (u + 0x7fffu + ((u >> 16) & 1u)) >> 16;
  return (short)(unsigned short)r;
}

__device__ inline float bf2f(short s) {
  return __uint_as_float(((unsigned)(unsigned short)s) << 16);
}

__device__ inline unsigned pkbf(float a, float b) {
  unsigned r;
  asm("v_cvt_pk_bf16_f32 %0, %1, %2" : "=v"(r) : "v"(a), "v"(b));
  return r;
}

__global__ void cast_x_kernel(const float* __restrict__ x, short* __restrict__ xb, int total) {
  int i = blockIdx.x * 256 + threadIdx.x;
  if (i < total) xb[i] = f2bf(x[i]);
}

// generic pack w[K][N] (f32) -> p[(k>>3)][n][k&7] (bf16)
__global__ void pack_w_kernel(const float* __restrict__ w, short* __restrict__ p, int K, int N) {
  int idx = blockIdx.x * 256 + threadIdx.x;
  if (idx >= K * N) return;
  int k = idx / N, n = idx - k * N;
  p[(size_t)(k >> 3) * N * 8 + (size_t)n * 8 + (k & 7)] = f2bf(w[idx]);
}

// e_w1 [768][512] split: rows 0..255 -> w1abp half0, 256..511 -> w1abp half1 (N=1024),
// rows 512..767 -> w1cp (N=512). Same MFMA-native (k>>3, n, k&7) layout.
__global__ void pack_ew1_kernel(const float* __restrict__ w, short* __restrict__ w1abp,
                                short* __restrict__ w1cp) {
  int idx = blockIdx.x * 256 + threadIdx.x;
  if (idx >= 768 * 512) return;
  int k = idx >> 9, n = idx & 511;
  short v = f2bf(w[idx]);
  if (k < 256) {
    w1abp[(size_t)(k >> 3) * 1024 * 8 + (size_t)n * 8 + (k & 7)] = v;
  } else if (k < 512) {
    int kk = k - 256;
    w1abp[(size_t)(kk >> 3) * 1024 * 8 + (size_t)(512 + n) * 8 + (kk & 7)] = v;
  } else {
    int kk = k - 512;
    w1cp[(size_t)(kk >> 3) * 512 * 8 + (size_t)n * 8 + (kk & 7)] = v;
  }
}

// ---------------- CSR build ----------------
__global__ void hist_kernel(const int* __restrict__ ei, int* __restrict__ deg) {
  int e = blockIdx.x * 256 + threadIdx.x;
  if (e < NEDGE) {
    int j = ei[NEDGE + e]; j = min(max(j, 0), NNODE - 1);
    atomicAdd(&deg[j], 1);
  }
}

__global__ void scan_kernel(const int* __restrict__ deg, int* __restrict__ row_start) {
  __shared__ int part[256];
  int t = threadIdx.x;
  const int CH = 40;
  int base = t * CH;
  int s = 0;
  for (int i = 0; i < CH; i++) {
    int idx = base + i;
    s += (idx < NNODE) ? deg[idx] : 0;
  }
  part[t] = s;
  __syncthreads();
  for (int off = 1; off < 256; off <<= 1) {
    int v = (t >= off) ? part[t - off] : 0;
    __syncthreads();
    part[t] += v;
    __syncthreads();
  }
  int run = (t == 0) ? 0 : part[t - 1];
  for (int i = 0; i < CH; i++) {
    int idx = base + i;
    if (idx < NNODE) { row_start[idx] = run; run += deg[idx]; }
  }
  if (t == 255) row_start[NNODE] = part[255];
}

__global__ void scatter_kernel(const int* __restrict__ ei, const int* __restrict__ row_start,
                               int* __restrict__ cursor, int* __restrict__ csr) {
  int e = blockIdx.x * 256 + threadIdx.x;
  if (e < NEDGE) {
    int j = ei[NEDGE + e]; j = min(max(j, 0), NNODE - 1);
    int p = atomicAdd(&cursor[j], 1);
    csr[row_start[j] + p] = e;
  }
}

// ---------------- precomp: Pab = x @ [W1a | W1b], packed-fragment bf16 ----------------
__global__ __launch_bounds__(256, 2)
void precomp_pab(const short* __restrict__ xb, const short* __restrict__ w1abp,
                 short* __restrict__ pab) {
  __shared__ __align__(16) short abuf[2048 * 8];  // 32 KB swizzled

  const int tid  = threadIdx.x;
  const int lane = tid & 63;
  const int wid  = tid >> 6;
  const int lhi  = lane >> 4;
  const int llo  = lane & 15;
  const int swz  = llo & 7;
  const int m0   = blockIdx.x * 64;
  const int h    = blockIdx.y;

  #pragma unroll
  for (int q = 0; q < 8; q++) {
    int S = wid * 512 + q * 64 + lane;
    int row = S >> 5;
    int segp = S & 31;
    int seg = segp ^ (row & 7);
    int rowg = min(m0 + row, NNODE - 1);
    __builtin_amdgcn_global_load_lds(
        (const int*)((const char*)xb + (size_t)rowg * 512 + seg * 16),
        (int*)(abuf + (size_t)(wid * 512 + q * 64) * 8), 16, 0, 0);
  }
  __syncthreads();

  f32x4 acc1[4][8] = {};
  const bf16x8* bp1 = (const bf16x8*)w1abp;
  #pragma unroll
  for (int kk = 0; kk < 256; kk += 32) {
    const int ks = kk >> 3;
    bf16x8 a[4];
    #pragma unroll
    for (int mf = 0; mf < 4; mf++)
      a[mf] = *(const bf16x8*)(abuf + ((mf * 16 + llo) * 32 + ((ks + lhi) ^ swz)) * 8);
    const bf16x8* bb = bp1 + (size_t)(ks + lhi) * 1024 + h * 512 + wid * 128 + llo;
    #pragma unroll
    for (int nf = 0; nf < 8; nf++) {
      bf16x8 b = bb[nf * 16];
      #pragma unroll
      for (int mf = 0; mf < 4; mf++)
        acc1[mf][nf] = __builtin_amdgcn_mfma_f32_16x16x32_bf16(a[mf], b, acc1[mf][nf], 0, 0, 0);
    }
  }

  #pragma unroll
  for (int mf = 0; mf < 4; mf++) {
    #pragma unroll
    for (int r = 0; r < 4; r++) {
      int row = m0 + mf * 16 + lhi * 4 + r;
      if (row < NNODE) {
        u32x4 wv = { pkbf(acc1[mf][0][r], acc1[mf][1][r]),
                     pkbf(acc1[mf][2][r], acc1[mf][3][r]),
                     pkbf(acc1[mf][4][r], acc1[mf][5][r]),
                     pkbf(acc1[mf][6][r], acc1[mf][7][r]) };
        *(u32x4*)(pab + (size_t)row * 1024 + h * 512 + llo * 32 + wid * 8) = wv;
      }
    }
  }
}

// ---------------- edge kernel (CSR-ordered, fused aggregation) ----------------
// Block b: edges csr[64b..64b+63] (grouped by j). hidden = relu(ea@W1c + Pab[i]
// + Pab[j] + b1); new_edge = ea + LN(hidden@W2 + b2). ea read ONCE (nt loads);
// residual snapshotted from the LDS bf16 tile into regs before hid overwrite.
__global__ __launch_bounds__(256, 2)
void fused_edge(const int* __restrict__ ei,
                const int* __restrict__ csr,
                const float* __restrict__ ea,
                const short* __restrict__ pab,
                const short* __restrict__ w1cp,
                const float* __restrict__ b1,
                const short* __restrict__ w2p,
                const float* __restrict__ b2,
                const float* __restrict__ gam,
                const float* __restrict__ bet,
                float* __restrict__ out,
                float* __restrict__ aggf)
{
  // union region: abuf (32KB stage) -> hid (64KB bf16) -> outt (66.56KB f32)
  __shared__ __align__(16) char smem[66560];
  __shared__ int eidx[64], idxi[64], idxj[64];
  __shared__ float pS[256], pQ[256];

  short* abuf = (short*)smem;   // [64 rows][32 segs of 8] bf16, swizzled
  short* hid  = (short*)smem;   // [64][512] bf16, XOR-swizzled
  float* outt = (float*)smem;   // [64][260] f32

  const int tid  = threadIdx.x;
  const int lane = tid & 63;
  const int wid  = tid >> 6;
  const int lhi  = lane >> 4;
  const int llo  = lane & 15;
  const int swz  = llo & 7;
  const int m0   = blockIdx.x * 64;
  const int bcol2 = wid * 64 + llo;

  if (tid < 64) {
    int e = csr[m0 + tid];
    eidx[tid] = e;
    int a = ei[e];
    int b = ei[NEDGE + e];
    idxi[tid] = min(max(a, 0), NNODE - 1);
    idxj[tid] = min(max(b, 0), NNODE - 1);
  }
  __syncthreads();

  // stage ea tile (64 gathered rows, f32 -> bf16, swizzled); rows read ONCE -> nt
  #pragma unroll
  for (int q = 0; q < 8; q++) {
    int S = q * 256 + tid;
    int row = S >> 5;
    int segp = S & 31;
    int seg = segp ^ (row & 7);
    const f32x4* src = (const f32x4*)(ea + (size_t)eidx[row] * 256 + seg * 8);
    f32x4 u0 = __builtin_nontemporal_load(src);
    f32x4 u1 = __builtin_nontemporal_load(src + 1);
    u32x4 qv = { pkbf(u0.x, u0.y), pkbf(u0.z, u0.w), pkbf(u1.x, u1.y), pkbf(u1.z, u1.w) };
    *(u32x4*)(abuf + (size_t)S * 8) = qv;
  }
  __syncthreads();

  // ---------------- GEMM_c: [64 x 256] @ [256 x 512] ----------------
  f32x4 acc1[4][8] = {};
  const bf16x8* bp1 = (const bf16x8*)w1cp;
  #pragma unroll
  for (int kk = 0; kk < 256; kk += 32) {
    const int ks = kk >> 3;
    bf16x8 a[4];
    #pragma unroll
    for (int mf = 0; mf < 4; mf++)
      a[mf] = *(const bf16x8*)(abuf + ((mf * 16 + llo) * 32 + ((ks + lhi) ^ swz)) * 8);
    const bf16x8* bb = bp1 + (size_t)(ks + lhi) * 512 + wid * 128 + llo;
    #pragma unroll
    for (int nf = 0; nf < 8; nf++) {
      bf16x8 b = bb[nf * 16];
      #pragma unroll
      for (int mf = 0; mf < 4; mf++)
        acc1[mf][nf] = __builtin_amdgcn_mfma_f32_16x16x32_bf16(a[mf], b, acc1[mf][nf], 0, 0, 0);
    }
  }

  // add gathered Pab rows (packed-fragment layout); j-side L2-local via CSR order
  #pragma unroll
  for (int mf = 0; mf < 4; mf++) {
    #pragma unroll
    for (int r = 0; r < 4; r++) {
      int row = mf * 16 + lhi * 4 + r;
      int gi = idxi[row], gj = idxj[row];
      bf16x8 pa = *(const bf16x8*)(pab + (size_t)gi * 1024 + llo * 32 + wid * 8);
      bf16x8 pb = *(const bf16x8*)(pab + (size_t)gj * 1024 + 512 + llo * 32 + wid * 8);
      #pragma unroll
      for (int nf = 0; nf < 8; nf++)
        acc1[mf][nf][r] += bf2f(pa[nf]) + bf2f(pb[nf]);
    }
  }

  // snapshot this thread's residual (bf16 ea) from abuf before hid overwrites it
  float resv[4][4][4];
  #pragma unroll
  for (int mf = 0; mf < 4; mf++) {
    #pragma unroll
    for (int r = 0; r < 4; r++) {
      int row = mf * 16 + lhi * 4 + r;
      #pragma unroll
      for (int nf = 0; nf < 4; nf++) {
        int col = bcol2 + nf * 16;
        resv[mf][r][nf] = bf2f(abuf[row * 256 + (((col >> 3) ^ (row & 7)) << 3) + (col & 7)]);
      }
    }
  }
  __syncthreads();  // GEMM_c + residual LDS reads done before hid overwrites abuf

  // ---------------- bias + relu -> hid (XOR-swizzled, K=512) ----------------
  #pragma unroll
  for (int nf = 0; nf < 8; nf++) {
    int col = wid * 128 + nf * 16 + llo;
    float bb = b1[col];
    int cs = col >> 3, cl = col & 7;
    #pragma unroll
    for (int mf = 0; mf < 4; mf++) {
      #pragma unroll
      for (int r = 0; r < 4; r++) {
        int row = mf * 16 + lhi * 4 + r;
        float v = acc1[mf][nf][r] + bb;
        v = v > 0.f ? v : 0.f;
        hid[row * 512 + ((cs ^ (row & 7)) * 8) + cl] = f2bf(v);
      }
    }
  }
  __syncthreads();

  // ---------------- GEMM2: [64 x 512] @ [512 x 256] ----------------
  f32x4 acc2[4][4] = {};
  const bf16x8* bp2 = (const bf16x8*)w2p;
  #pragma unroll
  for (int kk = 0; kk < 512; kk += 32) {
    const int ks = kk >> 3;
    bf16x8 a[4];
    #pragma unroll
    for (int mf = 0; mf < 4; mf++) {
      int row = mf * 16 + llo;
      a[mf] = *(const bf16x8*)(hid + row * 512 + (((ks + lhi) ^ swz) * 8));
    }
    const bf16x8* bb = bp2 + (size_t)(ks + lhi) * 256 + bcol2;
    #pragma unroll
    for (int nf = 0; nf < 4; nf++) {
      bf16x8 b = bb[nf * 16];
      #pragma unroll
      for (int mf = 0; mf < 4; mf++)
        acc2[mf][nf] = __builtin_amdgcn_mfma_f32_16x16x32_bf16(a[mf], b, acc2[mf][nf], 0, 0, 0);
    }
  }

  // ---------------- LayerNorm stats ----------------
  float bb2[4], gg[4], be[4];
  #pragma unroll
  for (int nf = 0; nf < 4; nf++) {
    int col = bcol2 + nf * 16;
    bb2[nf] = b2[col]; gg[nf] = gam[col]; be[nf] = bet[col];
  }
  #pragma unroll
  for (int mf = 0; mf < 4; mf++)
    #pragma unroll
    for (int nf = 0; nf < 4; nf++)
      #pragma unroll
      for (int r = 0; r < 4; r++)
        acc2[mf][nf][r] += bb2[nf];

  float S[4][4], Q[4][4];
  #pragma unroll
  for (int mf = 0; mf < 4; mf++) {
    #pragma unroll
    for (int r = 0; r < 4; r++) {
      float s = 0.f, q = 0.f;
      #pragma unroll
      for (int nf = 0; nf < 4; nf++) {
        float v = acc2[mf][nf][r];
        s += v; q += v * v;
      }
      S[mf][r] = s; Q[mf][r] = q;
    }
  }
  #pragma unroll
  for (int m = 1; m <= 8; m <<= 1) {
    #pragma unroll
    for (int mf = 0; mf < 4; mf++)
      #pragma unroll
      for (int r = 0; r < 4; r++) {
        S[mf][r] += __shfl_xor(S[mf][r], m);
        Q[mf][r] += __shfl_xor(Q[mf][r], m);
      }
  }
  if (llo == 0) {
    #pragma unroll
    for (int mf = 0; mf < 4; mf++)
      #pragma unroll
      for (int r = 0; r < 4; r++) {
        int row = mf * 16 + lhi * 4 + r;
        pS[wid * 64 + row] = S[mf][r];
        pQ[wid * 64 + row] = Q[mf][r];
      }
  }
  __syncthreads();  // also guarantees all GEMM2 hid reads complete

  float mu[4][4], rsv[4][4];
  #pragma unroll
  for (int mf = 0; mf < 4; mf++) {
    #pragma unroll
    for (int r = 0; r < 4; r++) {
      int row = mf * 16 + lhi * 4 + r;
      float s = pS[row] + pS[64 + row] + pS[128 + row] + pS[192 + row];
      float q = pQ[row] + pQ[64 + row] + pQ[128 + row] + pQ[192 + row];
      float m_ = s * (1.f / 256.f);
      mu[mf][r]  = m_;
      rsv[mf][r] = rsqrtf(q * (1.f / 256.f) - m_ * m_ + 1e-5f);
    }
  }

  // write final new_edge (LN + residual) into outt[64][260] f32 (overwrites hid)
  #pragma unroll
  for (int mf = 0; mf < 4; mf++) {
    #pragma unroll
    for (int r = 0; r < 4; r++) {
      int row = mf * 16 + lhi * 4 + r;
      #pragma unroll
      for (int nf = 0; nf < 4; nf++) {
        float v = (acc2[mf][nf][r] - mu[mf][r]) * rsv[mf][r] * gg[nf] + be[nf]
                  + resv[mf][r][nf];
        outt[row * 260 + bcol2 + nf * 16] = v;
      }
    }
  }
  __syncthreads();

  // ---------------- store loop: full 1KB contiguous rows ----------------
  #pragma unroll
  for (int it = 0; it < 16; it++) {
    int row = it * 4 + wid;
    int e = eidx[row];
    f32x4 o4 = *((const f32x4*)(outt + row * 260) + lane);
    __builtin_nontemporal_store(o4, (f32x4*)(out + (size_t)e * 256) + lane);
  }
  __syncthreads();

  // ---------------- fused segment-sum over j (sorted within block) ----------------
  {
    int c = tid;  // column 0..255
    float acc = 0.f;
    int cj = idxj[0];
    #pragma unroll 8
    for (int r = 0; r < 64; r++) {
      int jr = idxj[r];
      if (jr != cj) {  // uniform branch
        atomicAdd(&aggf[(size_t)cj * 256 + c], acc);
        acc = 0.f; cj = jr;
      }
      acc += outt[r * 260 + c];
    }
    atomicAdd(&aggf[(size_t)cj * 256 + c], acc);
  }
}

// ---------------- node kernel (R3-proven structure; f32 agg input) ----------------
__global__ __launch_bounds__(256, 2)
void fused_node(const float* __restrict__ x,
                const short* __restrict__ xb,
                const float* __restrict__ aggf,
                const short* __restrict__ w1p,
                const float* __restrict__ b1,
                const short* __restrict__ w2p,
                const float* __restrict__ b2,
                const float* __restrict__ gam,
                const float* __restrict__ bet,
                float* __restrict__ out)
{
  constexpr int HP = 520;
  __shared__ __align__(16) short hid[64 * HP];
  __shared__ float pS[4][64], pQ[4][64];

  const int tid  = threadIdx.x;
  const int lane = tid & 63;
  const int wid  = tid >> 6;
  const int m0   = blockIdx.x * 64;
  const int lhi  = lane >> 4;
  const int llo  = lane & 15;

  const short* pI[4]; const float* pJ[4];
  #pragma unroll
  for (int mf = 0; mf < 4; mf++) {
    int rr = min(m0 + mf * 16 + llo, NNODE - 1);
    pI[mf] = xb + (size_t)rr * DD;
    pJ[mf] = aggf + (size_t)rr * DD;
  }

  f32x4 acc1[4][8] = {};
  const bf16x8* bp1 = (const bf16x8*)w1p;
  const int bcol1 = wid * 128 + llo;

  #pragma unroll
  for (int s = 0; s < 8; s++) {
    #pragma unroll
    for (int kk = 0; kk < 64; kk += 32) {
      const int ko = s * 64 + kk + lhi * 8;
      bf16x8 a[4];
      #pragma unroll
      for (int mf = 0; mf < 4; mf++) {
        if (s < 4) {
          a[mf] = *(const bf16x8*)(pI[mf] + ko);
        } else {
          const float* fp = pJ[mf] + (ko - 256);
          f32x4 u0 = *(const f32x4*)fp;
          f32x4 u1 = *(const f32x4*)(fp + 4);
          u32x4 q = { pkbf(u0.x, u0.y), pkbf(u0.z, u0.w),
                      pkbf(u1.x, u1.y), pkbf(u1.z, u1.w) };
          a[mf] = __builtin_bit_cast(bf16x8, q);
        }
      }
      const bf16x8* bb = bp1 + (size_t)(s * 8 + (kk >> 3) + lhi) * 512 + bcol1;
      #pragma unroll
      for (int nf = 0; nf < 8; nf++) {
        bf16x8 b = bb[nf * 16];
        #pragma unroll
        for (int mf = 0; mf < 4; mf++)
          acc1[mf][nf] = __builtin_amdgcn_mfma_f32_16x16x32_bf16(a[mf], b, acc1[mf][nf], 0, 0, 0);
      }
    }
  }

  #pragma unroll
  for (int nf = 0; nf < 8; nf++) {
    int col = wid * 128 + nf * 16 + llo;
    float bb = b1[col];
    #pragma unroll
    for (int mf = 0; mf < 4; mf++) {
      #pragma unroll
      for (int r = 0; r < 4; r++) {
        float v = acc1[mf][nf][r] + bb;
        v = v > 0.f ? v : 0.f;
        hid[(mf * 16 + lhi * 4 + r) * HP + col] = f2bf(v);
      }
    }
  }
  __syncthreads();

  f32x4 acc2[4][4] = {};
  const bf16x8* bp2 = (const bf16x8*)w2p;
  const int bcol2 = wid * 64 + llo;
  #pragma unroll
  for (int kk = 0; kk < 512; kk += 32) {
    bf16x8 a[4];
    #pragma unroll
    for (int mf = 0; mf < 4; mf++)
      a[mf] = *(const bf16x8*)(hid + (mf * 16 + llo) * HP + kk + lhi * 8);
    const bf16x8* bb = bp2 + (size_t)((kk >> 3) + lhi) * 256 + bcol2;
    #pragma unroll
    for (int nf = 0; nf < 4; nf++) {
      bf16x8 b = bb[nf * 16];
      #pragma unroll
      for (int mf = 0; mf < 4; mf++)
        acc2[mf][nf] = __builtin_amdgcn_mfma_f32_16x16x32_bf16(a[mf], b, acc2[mf][nf], 0, 0, 0);
    }
  }

  float bb2[4], gg[4], be[4];
  #pragma unroll
  for (int nf = 0; nf < 4; nf++) {
    int col = bcol2 + nf * 16;
    bb2[nf] = b2[col]; gg[nf] = gam[col]; be[nf] = bet[col];
  }
  #pragma unroll
  for (int mf = 0; mf < 4; mf++)
    #pragma unroll
    for (int nf = 0; nf < 4; nf++)
      #pragma unroll
      for (int r = 0; r < 4; r++)
        acc2[mf][nf][r] += bb2[nf];

  float S[4][4], Q[4][4];
  #pragma unroll
  for (int mf = 0; mf < 4; mf++) {
    #pragma unroll
    for (int r = 0; r < 4; r++) {
      float s = 0.f, q = 0.f;
      #pragma unroll
      for (int nf = 0; nf < 4; nf++) {
        float v = acc2[mf][nf][r];
        s += v; q += v * v;
      }
      S[mf][r] = s; Q[mf][r] = q;
    }
  }
  #pragma unroll
  for (int m = 1; m <= 8; m <<= 1) {
    #pragma unroll
    for (int mf = 0; mf < 4; mf++)
      #pragma unroll
      for (int r = 0; r < 4; r++) {
        S[mf][r] += __shfl_xor(S[mf][r], m);
        Q[mf][r] += __shfl_xor(Q[mf][r], m);
      }
  }
  if (llo == 0) {
    #pragma unroll
    for (int mf = 0; mf < 4; mf++)
      #pragma unroll
      for (int r = 0; r < 4; r++) {
        int row = mf * 16 + lhi * 4 + r;
        pS[wid][row] = S[mf][r];
        pQ[wid][row] = Q[mf][r];
      }
  }
  __syncthreads();

  float mu[4][4], rsv[4][4];
  #pragma unroll
  for (int mf = 0; mf < 4; mf++) {
    #pragma unroll
    for (int r = 0; r < 4; r++) {
      int row = mf * 16 + lhi * 4 + r;
      float s = pS[0][row] + pS[1][row] + pS[2][row] + pS[3][row];
      float q = pQ[0][row] + pQ[1][row] + pQ[2][row] + pQ[3][row];
      float m_ = s * (1.f / 256.f);
      mu[mf][r]  = m_;
      rsv[mf][r] = rsqrtf(q * (1.f / 256.f) - m_ * m_ + 1e-5f);
    }
  }

  #pragma unroll
  for (int mf = 0; mf < 4; mf++) {
    #pragma unroll
    for (int r = 0; r < 4; r++) {
      int grow = m0 + mf * 16 + lhi * 4 + r;
      if (grow >= NNODE) continue;
      const float* rp = x   + (size_t)grow * DD + bcol2;
      float*       op = out + (size_t)grow * DD + bcol2;
      #pragma unroll
      for (int nf = 0; nf < 4; nf++) {
        float v = (acc2[mf][nf][r] - mu[mf][r]) * rsv[mf][r] * gg[nf] + be[nf] + rp[nf * 16];
        op[nf * 16] = v;
      }
    }
  }
}

extern "C" void kernel_launch(void* const* d_in, const int* in_sizes, int n_in,
                              void* d_out, int out_size, void* d_ws, size_t ws_size,
                              hipStream_t stream) {
  const float* x      = (const float*)d_in[0];
  const int*   ei     = (const int*)  d_in[1];
  const float* ea     = (const float*)d_in[2];
  const float* e_w1   = (const float*)d_in[3];
  const float* e_b1   = (const float*)d_in[4];
  const float* e_w2   = (const float*)d_in[5];
  const float* e_b2   = (const float*)d_in[6];
  const float* e_g    = (const float*)d_in[7];
  const float* e_beta = (const float*)d_in[8];
  const float* n_w1   = (const float*)d_in[9];
  const float* n_b1   = (const float*)d_in[10];
  const float* n_w2   = (const float*)d_in[11];
  const float* n_b2   = (const float*)d_in[12];
  const float* n_g    = (const float*)d_in[13];
  const float* n_beta = (const float*)d_in[14];

  float* out_x = (float*)d_out;
  float* out_e = (float*)d_out + (size_t)NNODE * DD;

  char* w = (char*)d_ws;
  short* xb    = (short*)(w);                   //  5,120,000 B
  short* pab   = (short*)(w + 5120000);         // 20,480,000 B
  short* w1abp = (short*)(w + 25600000);        //    524,288 B
  short* w1cp  = (short*)(w + 26124288);        //    262,144 B
  short* ew2p  = (short*)(w + 26386432);        //    262,144 B
  short* nw1p  = (short*)(w + 26648576);        //    524,288 B
  short* nw2p  = (short*)(w + 27172864);        //    262,144 B
  float* aggf  = (float*)(w + 27435008);        // 10,240,000 B
  int*   deg   = (int*)  (w + 37675008);        //     40,960 B
  int*   cur   = (int*)  (w + 37715968);        //     40,960 B
  int*   rs    = (int*)  (w + 37756928);        //     40,976 B
  int*   csr   = (int*)  (w + 37797904);        //    640,000 B -> ~38.4 MB total

  hipMemsetAsync(deg, 0, 81920, stream);                          // deg + cursor
  hipMemsetAsync(aggf, 0, (size_t)NNODE * DD * sizeof(float), stream);

  cast_x_kernel<<<(NNODE * DD + 255) / 256, 256, 0, stream>>>(x, xb, NNODE * DD);
  pack_ew1_kernel<<<(768 * 512 + 255) / 256, 256, 0, stream>>>(e_w1, w1abp, w1cp);
  pack_w_kernel<<<(512 * 512 + 255) / 256, 256, 0, stream>>>(n_w1, nw1p, 512, 512);
  pack_w_kernel<<<(512 * 256 + 255) / 256, 256, 0, stream>>>(e_w2, ew2p, 512, 256);
  pack_w_kernel<<<(512 * 256 + 255) / 256, 256, 0, stream>>>(n_w2, nw2p, 512, 256);

  hist_kernel<<<(NEDGE + 255) / 256, 256, 0, stream>>>(ei, deg);
  scan_kernel<<<1, 256, 0, stream>>>(deg, rs);
  scatter_kernel<<<(NEDGE + 255) / 256, 256, 0, stream>>>(ei, rs, cur, csr);

  precomp_pab<<<dim3((NNODE + 63) / 64, 2), 256, 0, stream>>>(xb, w1abp, pab);

  fused_edge<<<NEDGE / 64, 256, 0, stream>>>(ei, csr, ea, pab, w1cp, e_b1,
                                             ew2p, e_b2, e_g, e_beta, out_e, aggf);
  fused_node<<<(NNODE + 63) / 64, 256, 0, stream>>>(x, xb, aggf, nw1p, n_b1,
                                                    nw2p, n_b2, n_g, n_beta, out_x);
}